// Round 1
// baseline (1324.076 us; speedup 1.0000x reference)
//
#include <hip/hip_runtime.h>

#define EXPN 4
#define CAP 48
#define NSLOT 192   // EXPN*CAP
#define NBLK 4
#define NF 32

static __device__ __forceinline__ float relu_f(float x) { return fmaxf(x, 0.f); }

// ---------------- zero output ----------------
__global__ void k_zero(float4* __restrict__ p, int n4) {
  int i = blockIdx.x * blockDim.x + threadIdx.x;
  int stride = gridDim.x * blockDim.x;
  for (; i < n4; i += stride) p[i] = make_float4(0.f, 0.f, 0.f, 0.f);
}

// ---------------- classifier: conv3->32 + relu + GAP + linear -> argmax ----------------
__global__ __launch_bounds__(256) void k_classifier(
    const float* __restrict__ x, const float* __restrict__ cw,
    const float* __restrict__ cb, const float* __restrict__ fw,
    const float* __restrict__ fb, int* __restrict__ assign) {
  int n = blockIdx.x;
  int t = threadIdx.x;
  __shared__ float img[3 * 32 * 32];
  __shared__ float wl[32 * 27];
  __shared__ float part[256];
  __shared__ float cmean[32];
  for (int k = t; k < 3072; k += 256) img[k] = x[(size_t)n * 3072 + k];
  for (int k = t; k < 864; k += 256) wl[k] = cw[k];
  __syncthreads();
  int o = t >> 3;          // 0..31
  int ps = (t & 7) * 128;  // pixel start
  float bias = cb[o];
  float sum = 0.f;
  for (int pi = 0; pi < 128; ++pi) {
    int pix = ps + pi;
    int r = pix >> 5, c = pix & 31;
    float a = bias;
#pragma unroll
    for (int ci = 0; ci < 3; ++ci) {
#pragma unroll
      for (int ky = 0; ky < 3; ++ky) {
        int rr = r + ky - 1;
        if (rr < 0 || rr > 31) continue;
#pragma unroll
        for (int kx = 0; kx < 3; ++kx) {
          int cc = c + kx - 1;
          if (cc < 0 || cc > 31) continue;
          a += wl[(o * 3 + ci) * 9 + ky * 3 + kx] * img[ci * 1024 + rr * 32 + cc];
        }
      }
    }
    sum += relu_f(a);
  }
  part[t] = sum;
  __syncthreads();
  if (t < 32) {
    float s = 0.f;
    for (int k = 0; k < 8; ++k) s += part[t * 8 + k];
    cmean[t] = s * (1.f / 1024.f);
  }
  __syncthreads();
  if (t == 0) {
    float best = -1e30f;
    int bi = 0;
    for (int e = 0; e < EXPN; ++e) {
      float sc = fb[e];
      for (int oo = 0; oo < 32; ++oo) sc += cmean[oo] * fw[e * 32 + oo];
      if (sc > best) { best = sc; bi = e; }
    }
    assign[n] = bi;
  }
}

// ---------------- routing: first CAP images per expert (ascending index) ----------------
__global__ void k_route(const int* __restrict__ assign, int* __restrict__ slot_img, int N) {
  if (threadIdx.x == 0 && blockIdx.x == 0) {
    int cnt[EXPN];
    for (int e = 0; e < EXPN; ++e) cnt[e] = 0;
    for (int k = 0; k < NSLOT; ++k) slot_img[k] = -1;
    for (int n = 0; n < N; ++n) {
      int e = assign[n];
      if (cnt[e] < CAP) { slot_img[e * CAP + cnt[e]] = n; cnt[e]++; }
    }
  }
}

// ---------------- generic 3x3 conv at 32x32, Cout=32 ----------------
// MODE: 0 plain (+optional copy to out2), 1 relu, 2 out += 0.1*acc (in-place on outbuf),
//       3 acc + hbuf
template <int CIN, int MODE>
__global__ __launch_bounds__(256) void k_conv_std(
    const float* __restrict__ inbuf,  // CIN==3: inputs [N][3][32][32] (gather); else [S][32][32][32]
    float* __restrict__ outbuf,       // [S][32][32][32]
    const float* __restrict__ hbuf,   // MODE 3
    float* __restrict__ out2,         // MODE 0 (head): copy of output (res init)
    const float* __restrict__ wglob, const float* __restrict__ bglob,
    int w_estride, int b_estride, const int* __restrict__ slot_img) {
  int slot = blockIdx.y;
  int img = slot_img[slot];
  if (img < 0) return;
  int e = slot / CAP;
  int band = blockIdx.x;  // 0..3
  int t = threadIdx.x;
  int og = t >> 6, r = (t >> 3) & 7, cg = t & 7;
  int row = band * 8 + r, c0 = cg * 4;

  __shared__ float wl[CIN * 32 * 9];
  constexpr int CCH = (CIN == 3) ? 3 : 16;
  __shared__ float tile[CCH * 10 * 34];

  const float* wsrc = wglob + (size_t)e * w_estride;
  for (int k = t; k < CIN * 32 * 9; k += 256) {
    int o = k / (CIN * 9);
    int rem = k % (CIN * 9);
    int ci = rem / 9, tap = rem % 9;
    wl[(ci * 32 + o) * 9 + tap] = wsrc[k];
  }
  const float* bsrc = bglob + (size_t)e * b_estride;
  const float* inb = (CIN == 3) ? (inbuf + (size_t)img * CIN * 1024)
                                : (inbuf + (size_t)slot * CIN * 1024);

  float acc[8][4];
#pragma unroll
  for (int oi = 0; oi < 8; ++oi) {
    float b = bsrc[og * 8 + oi];
#pragma unroll
    for (int p = 0; p < 4; ++p) acc[oi][p] = b;
  }

  for (int ch = 0; ch < CIN; ch += CCH) {
    __syncthreads();
    for (int k = t; k < CCH * 10 * 34; k += 256) {
      int ci = k / 340;
      int rem = k % 340;
      int lr = rem / 34, lc = rem % 34;
      int gr = band * 8 - 1 + lr, gc = lc - 1;
      float v = 0.f;
      if (gr >= 0 && gr < 32 && gc >= 0 && gc < 32)
        v = inb[((size_t)(ch + ci) * 32 + gr) * 32 + gc];
      tile[k] = v;
    }
    __syncthreads();
#pragma unroll
    for (int cil = 0; cil < CCH; ++cil) {
      int ci = ch + cil;
      float iv[3][6];
#pragma unroll
      for (int ky = 0; ky < 3; ++ky)
#pragma unroll
        for (int dx = 0; dx < 6; ++dx)
          iv[ky][dx] = tile[cil * 340 + (r + ky) * 34 + c0 + dx];
#pragma unroll
      for (int oi = 0; oi < 8; ++oi) {
        const float* w9 = &wl[((size_t)ci * 32 + og * 8 + oi) * 9];
#pragma unroll
        for (int ky = 0; ky < 3; ++ky)
#pragma unroll
          for (int kx = 0; kx < 3; ++kx) {
            float wv = w9[ky * 3 + kx];
#pragma unroll
            for (int p = 0; p < 4; ++p) acc[oi][p] += wv * iv[ky][p + kx];
          }
      }
    }
  }

#pragma unroll
  for (int oi = 0; oi < 8; ++oi) {
    int o = og * 8 + oi;
    size_t idx = (((size_t)slot * 32 + o) * 32 + row) * 32 + c0;
    float a0 = acc[oi][0], a1 = acc[oi][1], a2 = acc[oi][2], a3 = acc[oi][3];
    if constexpr (MODE == 1) {
      a0 = relu_f(a0); a1 = relu_f(a1); a2 = relu_f(a2); a3 = relu_f(a3);
    }
    if constexpr (MODE == 2) {
      float4 d = *(const float4*)&outbuf[idx];
      a0 = d.x + 0.1f * a0; a1 = d.y + 0.1f * a1;
      a2 = d.z + 0.1f * a2; a3 = d.w + 0.1f * a3;
    }
    if constexpr (MODE == 3) {
      float4 hh = *(const float4*)&hbuf[idx];
      a0 += hh.x; a1 += hh.y; a2 += hh.z; a3 += hh.w;
    }
    float4 v = make_float4(a0, a1, a2, a3);
    *(float4*)&outbuf[idx] = v;
    if constexpr (MODE == 0) {
      if (out2) *(float4*)&out2[idx] = v;
    }
  }
}

// ---------------- upscale conv (32 -> 128) + fused pixel shuffle ----------------
// HW = input resolution (32 for up1, 64 for up2). gridDim.z = conv-channel group (4x32).
template <int HW>
__global__ __launch_bounds__(256) void k_conv_up(
    const float* __restrict__ inbuf,  // [S][32][HW][HW] (global slot)
    float* __restrict__ outbuf,       // [CH][32][2HW][2HW] (local slot)
    const float* __restrict__ wglob, const float* __restrict__ bglob,
    const int* __restrict__ slot_img, int slot0) {
  int lslot = blockIdx.y;
  int slot = slot0 + lslot;
  int img = slot_img[slot];
  if (img < 0) return;
  int e = slot / CAP;
  int g = blockIdx.z;  // 0..3
  constexpr int NBAND = HW / 8;
  int band = blockIdx.x % NBAND;
  int half = blockIdx.x / NBAND;  // 0..HW/32-1
  int t = threadIdx.x;
  int og = t >> 6, r = (t >> 3) & 7, cg = t & 7;
  int row = band * 8 + r, c0 = half * 32 + cg * 4;

  __shared__ float wl[32 * 32 * 9];
  __shared__ float tile[16 * 10 * 34];

  const float* wsrc = wglob + ((size_t)e * 128 + g * 32) * (32 * 9);
  for (int k = t; k < 32 * 32 * 9; k += 256) {
    int o = k / 288;
    int rem = k % 288;
    int ci = rem / 9, tap = rem % 9;
    wl[(ci * 32 + o) * 9 + tap] = wsrc[k];
  }
  const float* bsrc = bglob + (size_t)e * 128 + g * 32;
  const float* inb = inbuf + (size_t)slot * 32 * HW * HW;

  float acc[8][4];
#pragma unroll
  for (int oi = 0; oi < 8; ++oi) {
    float b = bsrc[og * 8 + oi];
#pragma unroll
    for (int p = 0; p < 4; ++p) acc[oi][p] = b;
  }

  for (int ch = 0; ch < 32; ch += 16) {
    __syncthreads();
    for (int k = t; k < 16 * 10 * 34; k += 256) {
      int ci = k / 340;
      int rem = k % 340;
      int lr = rem / 34, lc = rem % 34;
      int gr = band * 8 - 1 + lr, gc = half * 32 - 1 + lc;
      float v = 0.f;
      if (gr >= 0 && gr < HW && gc >= 0 && gc < HW)
        v = inb[((size_t)(ch + ci) * HW + gr) * HW + gc];
      tile[k] = v;
    }
    __syncthreads();
#pragma unroll
    for (int cil = 0; cil < 16; ++cil) {
      int ci = ch + cil;
      float iv[3][6];
#pragma unroll
      for (int ky = 0; ky < 3; ++ky)
#pragma unroll
        for (int dx = 0; dx < 6; ++dx)
          iv[ky][dx] = tile[cil * 340 + (r + ky) * 34 + cg * 4 + dx];
#pragma unroll
      for (int oi = 0; oi < 8; ++oi) {
        const float* w9 = &wl[((size_t)ci * 32 + og * 8 + oi) * 9];
#pragma unroll
        for (int ky = 0; ky < 3; ++ky)
#pragma unroll
          for (int kx = 0; kx < 3; ++kx) {
            float wv = w9[ky * 3 + kx];
#pragma unroll
            for (int p = 0; p < 4; ++p) acc[oi][p] += wv * iv[ky][p + kx];
          }
      }
    }
  }

  // pixel-shuffled store: conv ch co -> out[cc][2y+ry][2x+rx]
#pragma unroll
  for (int oi = 0; oi < 8; ++oi) {
    int co = g * 32 + og * 8 + oi;
    int cc = co >> 2, ry = (co >> 1) & 1, rx = co & 1;
    int oy = 2 * row + ry;
#pragma unroll
    for (int p = 0; p < 4; ++p) {
      int ox = 2 * (c0 + p) + rx;
      outbuf[(((size_t)lslot * 32 + cc) * (2 * HW) + oy) * (2 * HW) + ox] = acc[oi][p];
    }
  }
}

// ---------------- tail conv (32 -> 3) at 128x128, gather-write to output ----------------
__global__ __launch_bounds__(256) void k_tail(
    const float* __restrict__ inbuf,  // [CH][32][128][128] (local slot)
    float* __restrict__ out,          // [N][3][128][128]
    const float* __restrict__ wglob, const float* __restrict__ bglob,
    const int* __restrict__ slot_img, int slot0) {
  int lslot = blockIdx.y;
  int slot = slot0 + lslot;
  int img = slot_img[slot];
  if (img < 0) return;
  int e = slot / CAP;
  int band = blockIdx.x;  // 0..15
  int t = threadIdx.x;
  int r = t >> 5, cg = t & 31;
  int row = band * 8 + r, c0 = cg * 4;

  __shared__ float wl[32 * 3 * 9];
  __shared__ float tile[8 * 10 * 130];

  const float* wsrc = wglob + (size_t)e * 3 * 32 * 9;
  for (int k = t; k < 864; k += 256) {
    int o = k / 288;
    int rem = k % 288;
    int ci = rem / 9, tap = rem % 9;
    wl[(ci * 3 + o) * 9 + tap] = wsrc[k];
  }
  const float* bsrc = bglob + (size_t)e * 3;
  const float* inb = inbuf + (size_t)lslot * 32 * 16384;

  float acc[3][4];
#pragma unroll
  for (int oi = 0; oi < 3; ++oi) {
    float b = bsrc[oi];
#pragma unroll
    for (int p = 0; p < 4; ++p) acc[oi][p] = b;
  }

  for (int ch = 0; ch < 32; ch += 8) {
    __syncthreads();
    for (int k = t; k < 8 * 10 * 130; k += 256) {
      int ci = k / 1300;
      int rem = k % 1300;
      int lr = rem / 130, lc = rem % 130;
      int gr = band * 8 - 1 + lr, gc = lc - 1;
      float v = 0.f;
      if (gr >= 0 && gr < 128 && gc >= 0 && gc < 128)
        v = inb[((size_t)(ch + ci) * 128 + gr) * 128 + gc];
      tile[k] = v;
    }
    __syncthreads();
#pragma unroll
    for (int cil = 0; cil < 8; ++cil) {
      int ci = ch + cil;
      float iv[3][6];
#pragma unroll
      for (int ky = 0; ky < 3; ++ky)
#pragma unroll
        for (int dx = 0; dx < 6; ++dx)
          iv[ky][dx] = tile[cil * 1300 + (r + ky) * 130 + c0 + dx];
#pragma unroll
      for (int oi = 0; oi < 3; ++oi) {
        const float* w9 = &wl[((size_t)ci * 3 + oi) * 9];
#pragma unroll
        for (int ky = 0; ky < 3; ++ky)
#pragma unroll
          for (int kx = 0; kx < 3; ++kx) {
            float wv = w9[ky * 3 + kx];
#pragma unroll
            for (int p = 0; p < 4; ++p) acc[oi][p] += wv * iv[ky][p + kx];
          }
      }
    }
  }

#pragma unroll
  for (int oi = 0; oi < 3; ++oi) {
    size_t idx = (((size_t)img * 3 + oi) * 128 + row) * 128 + c0;
    *(float4*)&out[idx] = make_float4(acc[oi][0], acc[oi][1], acc[oi][2], acc[oi][3]);
  }
}

extern "C" void kernel_launch(void* const* d_in, const int* in_sizes, int n_in,
                              void* d_out, int out_size, void* d_ws, size_t ws_size,
                              hipStream_t stream) {
  const float* inputs = (const float*)d_in[0];
  const float* cls_w = (const float*)d_in[1];
  const float* cls_b = (const float*)d_in[2];
  const float* cls_fw = (const float*)d_in[3];
  const float* cls_fb = (const float*)d_in[4];
  const float* head_w = (const float*)d_in[5];
  const float* head_b = (const float*)d_in[6];
  const float* rb_w1 = (const float*)d_in[7];
  const float* rb_b1 = (const float*)d_in[8];
  const float* rb_w2 = (const float*)d_in[9];
  const float* rb_b2 = (const float*)d_in[10];
  const float* end_w = (const float*)d_in[11];
  const float* end_b = (const float*)d_in[12];
  const float* up_w1 = (const float*)d_in[13];
  const float* up_b1 = (const float*)d_in[14];
  const float* up_w2 = (const float*)d_in[15];
  const float* up_b2 = (const float*)d_in[16];
  const float* tail_w = (const float*)d_in[17];
  const float* tail_b = (const float*)d_in[18];
  float* out = (float*)d_out;
  char* ws = (char*)d_ws;

  int N = in_sizes[0] / (3 * 32 * 32);  // 128

  // workspace layout
  const size_t BUF = (size_t)NSLOT * 32 * 32 * 32 * 4;     // 25,165,824
  const size_t U1B = (size_t)NSLOT * 32 * 64 * 64 * 4;     // 100,663,296
  const size_t SLOT_U2 = (size_t)32 * 128 * 128 * 4;       // 2,097,152
  size_t o_h = 4096;
  size_t o_res = o_h + BUF;
  size_t o_tmp = o_h + 2 * BUF;
  size_t o_u1 = o_h + 3 * BUF;
  size_t o_u2full = o_u1 + U1B;

  int* assign = (int*)ws;
  int* slot_img = (int*)(ws + 512);
  float* h = (float*)(ws + o_h);
  float* res = (float*)(ws + o_res);
  float* tmp = (float*)(ws + o_tmp);
  float* u1 = (float*)(ws + o_u1);

  // u2 buffer: prefer tail of ws; else alias the (dead-by-then) h/res/tmp region
  float* u2;
  int CH;
  size_t tail_avail = (ws_size > o_u2full) ? (ws_size - o_u2full) : 0;
  int CH_tail = (int)(tail_avail / SLOT_U2);
  const int CH_alias = (int)((3 * BUF) / SLOT_U2);  // 36 slots
  if (CH_tail >= CH_alias) {
    u2 = (float*)(ws + o_u2full);
    CH = CH_tail < NSLOT ? CH_tail : NSLOT;
  } else {
    u2 = (float*)(ws + o_h);
    CH = CH_alias;
  }
  if (CH < 1) CH = 1;

  k_zero<<<2048, 256, 0, stream>>>((float4*)out, out_size / 4);
  k_classifier<<<N, 256, 0, stream>>>(inputs, cls_w, cls_b, cls_fw, cls_fb, assign);
  k_route<<<1, 64, 0, stream>>>(assign, slot_img, N);

  // head: conv 3->32, write h and res
  k_conv_std<3, 0><<<dim3(4, NSLOT), 256, 0, stream>>>(
      inputs, h, nullptr, res, head_w, head_b, 32 * 27, 32, slot_img);

  // ResBlocks
  for (int i = 0; i < NBLK; ++i) {
    k_conv_std<32, 1><<<dim3(4, NSLOT), 256, 0, stream>>>(
        res, tmp, nullptr, nullptr, rb_w1 + (size_t)i * 32 * 32 * 9, rb_b1 + i * 32,
        NBLK * 32 * 32 * 9, NBLK * 32, slot_img);
    k_conv_std<32, 2><<<dim3(4, NSLOT), 256, 0, stream>>>(
        tmp, res, nullptr, nullptr, rb_w2 + (size_t)i * 32 * 32 * 9, rb_b2 + i * 32,
        NBLK * 32 * 32 * 9, NBLK * 32, slot_img);
  }

  // body end + skip (res -> tmp)
  k_conv_std<32, 3><<<dim3(4, NSLOT), 256, 0, stream>>>(
      res, tmp, h, nullptr, end_w, end_b, 32 * 32 * 9, 32, slot_img);

  // up1: conv 32->128 at 32x32, shuffled into u1 [S][32][64][64]
  k_conv_up<32><<<dim3(4, NSLOT, 4), 256, 0, stream>>>(
      tmp, u1, up_w1, up_b1, slot_img, 0);

  // up2 + tail, chunked over slots
  for (int s0 = 0; s0 < NSLOT; s0 += CH) {
    int cur = (NSLOT - s0) < CH ? (NSLOT - s0) : CH;
    k_conv_up<64><<<dim3(16, cur, 4), 256, 0, stream>>>(
        u1, u2, up_w2, up_b2, slot_img, s0);
    k_tail<<<dim3(16, cur), 256, 0, stream>>>(
        u2, out, tail_w, tail_b, slot_img, s0);
  }
}

// Round 2
// 440.621 us; speedup vs baseline: 3.0050x; 3.0050x over previous
//
#include <hip/hip_runtime.h>

#define EXPN 4
#define CAP 48
#define NSLOT 192   // EXPN*CAP
#define NBLK 4

typedef __attribute__((ext_vector_type(8))) short bf16x8;
typedef __attribute__((ext_vector_type(4))) float f32x4;

static __device__ __forceinline__ float bf2f(unsigned short s) {
  union { unsigned u; float f; } c; c.u = ((unsigned)s) << 16; return c.f;
}
static __device__ __forceinline__ unsigned short f2bf(float f) {
  union { float f; unsigned u; } c; c.f = f;
  unsigned u = c.u;
  return (unsigned short)((u + 0x7fffu + ((u >> 16) & 1u)) >> 16);  // RNE
}
static __device__ __forceinline__ f32x4 mfma16(bf16x8 a, bf16x8 b, f32x4 c) {
  return __builtin_amdgcn_mfma_f32_16x16x32_bf16(a, b, c, 0, 0, 0);
}
static __device__ __forceinline__ float relu_f(float x) { return fmaxf(x, 0.f); }

// ---------------- zero output ----------------
__global__ void k_zero(float4* __restrict__ p, int n4) {
  int i = blockIdx.x * blockDim.x + threadIdx.x;
  int stride = gridDim.x * blockDim.x;
  for (; i < n4; i += stride) p[i] = make_float4(0.f, 0.f, 0.f, 0.f);
}

// ---------------- classifier: conv3->32 + relu + GAP + linear -> argmax ----------------
__global__ __launch_bounds__(256) void k_classifier(
    const float* __restrict__ x, const float* __restrict__ cw,
    const float* __restrict__ cb, const float* __restrict__ fw,
    const float* __restrict__ fb, int* __restrict__ assign) {
  int n = blockIdx.x;
  int t = threadIdx.x;
  __shared__ float img[3 * 32 * 32];
  __shared__ float wl[32 * 27];
  __shared__ float part[256];
  __shared__ float cmean[32];
  for (int k = t; k < 3072; k += 256) img[k] = x[(size_t)n * 3072 + k];
  for (int k = t; k < 864; k += 256) wl[k] = cw[k];
  __syncthreads();
  int o = t >> 3;
  int ps = (t & 7) * 128;
  float bias = cb[o];
  float sum = 0.f;
  for (int pi = 0; pi < 128; ++pi) {
    int pix = ps + pi;
    int r = pix >> 5, c = pix & 31;
    float a = bias;
#pragma unroll
    for (int ci = 0; ci < 3; ++ci) {
#pragma unroll
      for (int ky = 0; ky < 3; ++ky) {
        int rr = r + ky - 1;
        if (rr < 0 || rr > 31) continue;
#pragma unroll
        for (int kx = 0; kx < 3; ++kx) {
          int cc = c + kx - 1;
          if (cc < 0 || cc > 31) continue;
          a += wl[(o * 3 + ci) * 9 + ky * 3 + kx] * img[ci * 1024 + rr * 32 + cc];
        }
      }
    }
    sum += relu_f(a);
  }
  part[t] = sum;
  __syncthreads();
  if (t < 32) {
    float s = 0.f;
    for (int k = 0; k < 8; ++k) s += part[t * 8 + k];
    cmean[t] = s * (1.f / 1024.f);
  }
  __syncthreads();
  if (t == 0) {
    float best = -1e30f;
    int bi = 0;
    for (int e = 0; e < EXPN; ++e) {
      float sc = fb[e];
      for (int oo = 0; oo < 32; ++oo) sc += cmean[oo] * fw[e * 32 + oo];
      if (sc > best) { best = sc; bi = e; }
    }
    assign[n] = bi;
  }
}

// ---------------- routing ----------------
__global__ void k_route(const int* __restrict__ assign, int* __restrict__ slot_img, int N) {
  if (threadIdx.x == 0 && blockIdx.x == 0) {
    int cnt[EXPN];
    for (int e = 0; e < EXPN; ++e) cnt[e] = 0;
    for (int k = 0; k < NSLOT; ++k) slot_img[k] = -1;
    for (int n = 0; n < N; ++n) {
      int e = assign[n];
      if (cnt[e] < CAP) { slot_img[e * CAP + cnt[e]] = n; cnt[e]++; }
    }
  }
}

// ---------------- head: conv 3->32 fp32 VALU, store bf16 channel-last to h and res ----------------
__global__ __launch_bounds__(256) void k_head(
    const float* __restrict__ x, unsigned short* __restrict__ hbuf,
    unsigned short* __restrict__ resbuf, const float* __restrict__ wglob,
    const float* __restrict__ bglob, const int* __restrict__ slot_img) {
  int slot = blockIdx.y;
  int img = slot_img[slot];
  if (img < 0) return;
  int e = slot / CAP;
  int band = blockIdx.x;
  int t = threadIdx.x;
  int og = t >> 6, r = (t >> 3) & 7, cg = t & 7;
  int c0 = cg * 4;
  __shared__ float wl[3 * 32 * 9];
  __shared__ float tile[3 * 10 * 34];
  __shared__ __align__(16) unsigned short ostg[256 * 32];
  const float* wsrc = wglob + (size_t)e * 32 * 27;
  for (int k = t; k < 864; k += 256) {
    int o = k / 27;
    int rem = k % 27;
    int ci = rem / 9, tap = rem % 9;
    wl[(ci * 32 + o) * 9 + tap] = wsrc[k];
  }
  const float* bsrc = bglob + (size_t)e * 32;
  const float* inb = x + (size_t)img * 3072;
  for (int k = t; k < 3 * 10 * 34; k += 256) {
    int ci = k / 340;
    int rem = k % 340;
    int lr = rem / 34, lc = rem % 34;
    int gr = band * 8 - 1 + lr, gc = lc - 1;
    float v = 0.f;
    if (gr >= 0 && gr < 32 && gc >= 0 && gc < 32) v = inb[(ci * 32 + gr) * 32 + gc];
    tile[k] = v;
  }
  __syncthreads();
  float acc[8][4];
#pragma unroll
  for (int oi = 0; oi < 8; ++oi) {
    float b = bsrc[og * 8 + oi];
#pragma unroll
    for (int p = 0; p < 4; ++p) acc[oi][p] = b;
  }
#pragma unroll
  for (int ci = 0; ci < 3; ++ci) {
    float iv[3][6];
#pragma unroll
    for (int ky = 0; ky < 3; ++ky)
#pragma unroll
      for (int dx = 0; dx < 6; ++dx)
        iv[ky][dx] = tile[ci * 340 + (r + ky) * 34 + c0 + dx];
#pragma unroll
    for (int oi = 0; oi < 8; ++oi) {
      const float* w9 = &wl[((size_t)ci * 32 + og * 8 + oi) * 9];
#pragma unroll
      for (int ky = 0; ky < 3; ++ky)
#pragma unroll
        for (int kx = 0; kx < 3; ++kx) {
          float wv = w9[ky * 3 + kx];
#pragma unroll
          for (int p = 0; p < 4; ++p) acc[oi][p] += wv * iv[ky][p + kx];
        }
    }
  }
#pragma unroll
  for (int oi = 0; oi < 8; ++oi)
#pragma unroll
    for (int p = 0; p < 4; ++p)
      ostg[(r * 32 + c0 + p) * 32 + og * 8 + oi] = f2bf(acc[oi][p]);
  __syncthreads();
  for (int u = t; u < 1024; u += 256) {
    int px = u >> 2, c8 = (u & 3) * 8;
    int4 v = *(const int4*)&ostg[px * 32 + c8];
    size_t gi = ((size_t)slot * 1024 + band * 256 + px) * 32 + c8;
    *(int4*)&hbuf[gi] = v;
    *(int4*)&resbuf[gi] = v;
  }
}

// ---------------- MFMA conv 32->32 @32x32, bf16 channel-last ----------------
// MODE 1: out = relu(conv)   MODE 2: out = aux + 0.1*conv   MODE 3: out = conv + aux
template <int MODE>
__global__ __launch_bounds__(256) void k_rb(
    const unsigned short* __restrict__ inbuf, unsigned short* __restrict__ outbuf,
    const unsigned short* __restrict__ aux,
    const float* __restrict__ wglob, const float* __restrict__ bglob,
    int w_estride, int b_estride, const int* __restrict__ slot_img) {
  int slot = blockIdx.y;
  int img = slot_img[slot];
  if (img < 0) return;
  int e = slot / CAP;
  int band = blockIdx.x;  // 0..3
  int t = threadIdx.x;
  int w = t >> 6, l = t & 63;
  int col = l & 15, s4 = l >> 4;
  __shared__ __align__(16) unsigned short tile[4 * 10 * 34 * 8];  // [s][lr][lx][8ch]
  __shared__ __align__(16) unsigned short scr[4 * 16 * 32];       // per-wave [16px][32ch]
  const unsigned short* inb = inbuf + (size_t)slot * 32768;
  for (int u = t; u < 1360; u += 256) {
    int s = u / 340;
    int rem = u - s * 340;
    int lr = rem / 34, lx = rem - lr * 34;
    int gr = band * 8 - 1 + lr, gx = lx - 1;
    int4 v = make_int4(0, 0, 0, 0);
    if (gr >= 0 && gr < 32 && gx >= 0 && gx < 32)
      v = *(const int4*)&inb[(gr * 32 + gx) * 32 + s * 8];
    *(int4*)&tile[u * 8] = v;
  }
  const float* wsrc = wglob + (size_t)e * w_estride;
  const float* bsrc = bglob + (size_t)e * b_estride;
  bf16x8 Bf[9][2];
  float bias[2];
#pragma unroll
  for (int n = 0; n < 2; ++n) {
    int och = n * 16 + col;
    bias[n] = bsrc[och];
#pragma unroll
    for (int tap = 0; tap < 9; ++tap) {
      bf16x8 bb;
#pragma unroll
      for (int j = 0; j < 8; ++j)
        bb[j] = (short)f2bf(wsrc[((size_t)och * 32 + s4 * 8 + j) * 9 + tap]);
      Bf[tap][n] = bb;
    }
  }
  __syncthreads();
  int hs = w >> 1, r0 = (w & 1) * 4;
  f32x4 acc[4][2];
#pragma unroll
  for (int m = 0; m < 4; ++m)
#pragma unroll
    for (int n = 0; n < 2; ++n) acc[m][n] = (f32x4){bias[n], bias[n], bias[n], bias[n]};
  bf16x8 Af[3][3];
#pragma unroll
  for (int ky = 0; ky < 3; ++ky)
#pragma unroll
    for (int kx = 0; kx < 3; ++kx)
      Af[ky][kx] = *(const bf16x8*)&tile[((s4 * 10 + r0 + ky) * 34 + hs * 16 + kx + col) * 8];
#pragma unroll
  for (int r = 0; r < 4; ++r) {
    if (r > 0) {
#pragma unroll
      for (int kx = 0; kx < 3; ++kx)
        Af[(r + 2) % 3][kx] =
            *(const bf16x8*)&tile[((s4 * 10 + r0 + r + 2) * 34 + hs * 16 + kx + col) * 8];
    }
#pragma unroll
    for (int n = 0; n < 2; ++n)
#pragma unroll
      for (int ky = 0; ky < 3; ++ky)
#pragma unroll
        for (int kx = 0; kx < 3; ++kx)
          acc[r][n] = mfma16(Af[(r + ky) % 3][kx], Bf[ky * 3 + kx][n], acc[r][n]);
  }
  unsigned short* wscr = &scr[w * 512];
  unsigned short* outb = outbuf + (size_t)slot * 32768;
  const unsigned short* auxb = (MODE == 1) ? (const unsigned short*)0 : aux + (size_t)slot * 32768;
#pragma unroll
  for (int r = 0; r < 4; ++r) {
#pragma unroll
    for (int n = 0; n < 2; ++n)
#pragma unroll
      for (int reg = 0; reg < 4; ++reg) {
        float v = acc[r][n][reg];
        if (MODE == 1) v = relu_f(v);
        wscr[(s4 * 4 + reg) * 32 + n * 16 + col] = f2bf(v);
      }
    int px2 = l >> 2, c8 = (l & 3) * 8;
    int4 yv = *(const int4*)&wscr[px2 * 32 + c8];
    int grow = band * 8 + r0 + r, gx = hs * 16 + px2;
    size_t gi = ((size_t)grow * 32 + gx) * 32 + c8;
    if (MODE == 2 || MODE == 3) {
      const float sc = (MODE == 2) ? 0.1f : 1.0f;
      int4 av = *(const int4*)&auxb[gi];
      unsigned short* yp = (unsigned short*)&yv;
      unsigned short* ap = (unsigned short*)&av;
#pragma unroll
      for (int j = 0; j < 8; ++j) yp[j] = f2bf(bf2f(ap[j]) + sc * bf2f(yp[j]));
    }
    *(int4*)&outb[gi] = yv;
  }
}

// ---------------- MFMA conv 32->128 + pixel shuffle, bf16 channel-last ----------------
template <int HW>
__global__ __launch_bounds__(256) void k_up(
    const unsigned short* __restrict__ inbuf, unsigned short* __restrict__ outbuf,
    const float* __restrict__ wglob, const float* __restrict__ bglob,
    const int* __restrict__ slot_img, int slot0) {
  int lslot = blockIdx.y;
  int slot = slot0 + lslot;
  int img = slot_img[slot];
  if (img < 0) return;
  int e = slot / CAP;
  int band = blockIdx.x;  // 0..HW/8-1
  int t = threadIdx.x;
  int w = t >> 6, l = t & 63;
  int col = l & 15, s4 = l >> 4;
  constexpr int XP = HW + 2;
  __shared__ __align__(16) unsigned short tile[4 * 10 * XP * 8];
  __shared__ __align__(16) unsigned short scr[4 * 4 * 16 * 8];  // per-wave [ryrx][px][8cc]
  const unsigned short* inb = inbuf + (size_t)slot * 32 * HW * HW;
  for (int u = t; u < 4 * 10 * XP; u += 256) {
    int s = u / (10 * XP);
    int rem = u - s * (10 * XP);
    int lr = rem / XP, lx = rem - lr * XP;
    int gr = band * 8 - 1 + lr, gx = lx - 1;
    int4 v = make_int4(0, 0, 0, 0);
    if (gr >= 0 && gr < HW && gx >= 0 && gx < HW)
      v = *(const int4*)&inb[(gr * HW + gx) * 32 + s * 8];
    *(int4*)&tile[u * 8] = v;
  }
  const float* wsrc = wglob + (size_t)e * 128 * 288;
  const float* bsrc = bglob + (size_t)e * 128;
  bf16x8 Bf[9][2];
  float bias[2];
#pragma unroll
  for (int n = 0; n < 2; ++n) {
    int och = w * 32 + n * 16 + col;
    bias[n] = bsrc[och];
#pragma unroll
    for (int tap = 0; tap < 9; ++tap) {
      bf16x8 bb;
#pragma unroll
      for (int j = 0; j < 8; ++j)
        bb[j] = (short)f2bf(wsrc[((size_t)och * 32 + s4 * 8 + j) * 9 + tap]);
      Bf[tap][n] = bb;
    }
  }
  __syncthreads();
  unsigned short* wscr = &scr[w * 512];
  unsigned short* outb = outbuf + (size_t)(slot - slot0) * (2 * HW) * (2 * HW) * 32;
  for (int h = 0; h < HW / 16; ++h) {
    bf16x8 Af[3][3];
#pragma unroll
    for (int ky = 0; ky < 3; ++ky)
#pragma unroll
      for (int kx = 0; kx < 3; ++kx)
        Af[ky][kx] = *(const bf16x8*)&tile[((s4 * 10 + ky) * XP + h * 16 + kx + col) * 8];
#pragma unroll
    for (int r = 0; r < 8; ++r) {
      if (r > 0) {
#pragma unroll
        for (int kx = 0; kx < 3; ++kx)
          Af[(r + 2) % 3][kx] =
              *(const bf16x8*)&tile[((s4 * 10 + r + 2) * XP + h * 16 + kx + col) * 8];
      }
      f32x4 acc[2];
#pragma unroll
      for (int n = 0; n < 2; ++n) acc[n] = (f32x4){bias[n], bias[n], bias[n], bias[n]};
#pragma unroll
      for (int n = 0; n < 2; ++n)
#pragma unroll
        for (int ky = 0; ky < 3; ++ky)
#pragma unroll
          for (int kx = 0; kx < 3; ++kx)
            acc[n] = mfma16(Af[(r + ky) % 3][kx], Bf[ky * 3 + kx][n], acc[n]);
#pragma unroll
      for (int n = 0; n < 2; ++n) {
        int och = w * 32 + n * 16 + col;
        int ryrx = och & 3, ccl = (och >> 2) & 7;
#pragma unroll
        for (int reg = 0; reg < 4; ++reg)
          wscr[(ryrx * 16 + s4 * 4 + reg) * 8 + ccl] = f2bf(acc[n][reg]);
      }
      int ryrx2 = l >> 4, px2 = l & 15;
      int4 yv = *(const int4*)&wscr[(ryrx2 * 16 + px2) * 8];
      int ry = ryrx2 >> 1, rx = ryrx2 & 1;
      int oy = 2 * (band * 8 + r) + ry, ox = 2 * (h * 16 + px2) + rx;
      size_t oi = ((size_t)oy * (2 * HW) + ox) * 32 + w * 8;
      *(int4*)&outb[oi] = yv;
    }
  }
}

// ---------------- MFMA tail conv 32->3 @128x128, fp32 gather-write ----------------
__global__ __launch_bounds__(256) void k_tail(
    const unsigned short* __restrict__ inbuf, float* __restrict__ out,
    const float* __restrict__ wglob, const float* __restrict__ bglob,
    const int* __restrict__ slot_img, int slot0) {
  int lslot = blockIdx.y;
  int slot = slot0 + lslot;
  int img = slot_img[slot];
  if (img < 0) return;
  int e = slot / CAP;
  int band = blockIdx.x & 15, xh = blockIdx.x >> 4;
  int t = threadIdx.x;
  int w = t >> 6, l = t & 63;
  int col = l & 15, s4 = l >> 4;
  __shared__ __align__(16) unsigned short tile[4 * 10 * 66 * 8];
  const unsigned short* inb = inbuf + (size_t)lslot * 128 * 128 * 32;
  for (int u = t; u < 2640; u += 256) {
    int s = u / 660;
    int rem = u - s * 660;
    int lr = rem / 66, lx = rem - lr * 66;
    int gr = band * 8 - 1 + lr, gx = xh * 64 - 1 + lx;
    int4 v = make_int4(0, 0, 0, 0);
    if (gr >= 0 && gr < 128 && gx >= 0 && gx < 128)
      v = *(const int4*)&inb[(gr * 128 + gx) * 32 + s * 8];
    *(int4*)&tile[u * 8] = v;
  }
  bf16x8 Bf[9];
  float bias = 0.f;
  if (col < 3) bias = bglob[e * 3 + col];
#pragma unroll
  for (int tap = 0; tap < 9; ++tap) {
    bf16x8 bb;
#pragma unroll
    for (int j = 0; j < 8; ++j)
      bb[j] = (col < 3)
                  ? (short)f2bf(wglob[(((size_t)e * 3 + col) * 32 + s4 * 8 + j) * 9 + tap])
                  : (short)0;
    Bf[tap] = bb;
  }
  __syncthreads();
  int hh = w;  // 16-px half within the 64-wide region
  bf16x8 Af[3][3];
#pragma unroll
  for (int ky = 0; ky < 3; ++ky)
#pragma unroll
    for (int kx = 0; kx < 3; ++kx)
      Af[ky][kx] = *(const bf16x8*)&tile[((s4 * 10 + ky) * 66 + hh * 16 + kx + col) * 8];
#pragma unroll
  for (int r = 0; r < 8; ++r) {
    if (r > 0) {
#pragma unroll
      for (int kx = 0; kx < 3; ++kx)
        Af[(r + 2) % 3][kx] =
            *(const bf16x8*)&tile[((s4 * 10 + r + 2) * 66 + hh * 16 + kx + col) * 8];
    }
    f32x4 acc = (f32x4){bias, bias, bias, bias};
#pragma unroll
    for (int ky = 0; ky < 3; ++ky)
#pragma unroll
      for (int kx = 0; kx < 3; ++kx)
        acc = mfma16(Af[(r + ky) % 3][kx], Bf[ky * 3 + kx], acc);
    if (col < 3) {
      int grow = band * 8 + r, gx0 = xh * 64 + hh * 16 + s4 * 4;
      *(float4*)&out[(((size_t)img * 3 + col) * 128 + grow) * 128 + gx0] =
          make_float4(acc[0], acc[1], acc[2], acc[3]);
    }
  }
}

extern "C" void kernel_launch(void* const* d_in, const int* in_sizes, int n_in,
                              void* d_out, int out_size, void* d_ws, size_t ws_size,
                              hipStream_t stream) {
  const float* inputs = (const float*)d_in[0];
  const float* cls_w = (const float*)d_in[1];
  const float* cls_b = (const float*)d_in[2];
  const float* cls_fw = (const float*)d_in[3];
  const float* cls_fb = (const float*)d_in[4];
  const float* head_w = (const float*)d_in[5];
  const float* head_b = (const float*)d_in[6];
  const float* rb_w1 = (const float*)d_in[7];
  const float* rb_b1 = (const float*)d_in[8];
  const float* rb_w2 = (const float*)d_in[9];
  const float* rb_b2 = (const float*)d_in[10];
  const float* end_w = (const float*)d_in[11];
  const float* end_b = (const float*)d_in[12];
  const float* up_w1 = (const float*)d_in[13];
  const float* up_b1 = (const float*)d_in[14];
  const float* up_w2 = (const float*)d_in[15];
  const float* up_b2 = (const float*)d_in[16];
  const float* tail_w = (const float*)d_in[17];
  const float* tail_b = (const float*)d_in[18];
  float* out = (float*)d_out;
  char* ws = (char*)d_ws;

  int N = in_sizes[0] / 3072;  // 128

  int* assign = (int*)ws;
  int* slot_img = (int*)(ws + 512);
  const size_t ABUF = (size_t)NSLOT * 1024 * 32 * 2;  // 12,582,912
  const size_t U1B = (size_t)NSLOT * 64 * 64 * 32 * 2; // 50,331,648
  const size_t SLOT_U2 = (size_t)128 * 128 * 32 * 2;   // 1,048,576
  size_t o_h = 4096;
  unsigned short* h = (unsigned short*)(ws + o_h);
  unsigned short* res = (unsigned short*)(ws + o_h + ABUF);
  unsigned short* tmp = (unsigned short*)(ws + o_h + 2 * ABUF);
  unsigned short* u1 = (unsigned short*)(ws + o_h + 3 * ABUF);
  size_t o_u2full = o_h + 3 * ABUF + U1B;  // ~88 MB

  unsigned short* u2;
  int CH;
  size_t tail_avail = (ws_size > o_u2full) ? (ws_size - o_u2full) : 0;
  int CH_tail = (int)(tail_avail / SLOT_U2);
  const int CH_alias = (int)((3 * ABUF) / SLOT_U2);  // 36 (h/res/tmp dead after up1)
  if (CH_tail >= CH_alias) {
    u2 = (unsigned short*)(ws + o_u2full);
    CH = CH_tail < NSLOT ? CH_tail : NSLOT;
  } else {
    u2 = (unsigned short*)(ws + o_h);
    CH = CH_alias;
  }
  if (CH < 1) CH = 1;

  k_zero<<<2048, 256, 0, stream>>>((float4*)out, out_size / 4);
  k_classifier<<<N, 256, 0, stream>>>(inputs, cls_w, cls_b, cls_fw, cls_fb, assign);
  k_route<<<1, 64, 0, stream>>>(assign, slot_img, N);

  k_head<<<dim3(4, NSLOT), 256, 0, stream>>>(inputs, h, res, head_w, head_b, slot_img);

  for (int i = 0; i < NBLK; ++i) {
    k_rb<1><<<dim3(4, NSLOT), 256, 0, stream>>>(
        res, tmp, (const unsigned short*)0, rb_w1 + (size_t)i * 9216, rb_b1 + i * 32,
        NBLK * 9216, NBLK * 32, slot_img);
    k_rb<2><<<dim3(4, NSLOT), 256, 0, stream>>>(
        tmp, res, res, rb_w2 + (size_t)i * 9216, rb_b2 + i * 32,
        NBLK * 9216, NBLK * 32, slot_img);
  }

  k_rb<3><<<dim3(4, NSLOT), 256, 0, stream>>>(
      res, tmp, h, end_w, end_b, 9216, 32, slot_img);

  k_up<32><<<dim3(4, NSLOT), 256, 0, stream>>>(tmp, u1, up_w1, up_b1, slot_img, 0);

  for (int s0 = 0; s0 < NSLOT; s0 += CH) {
    int cur = (NSLOT - s0) < CH ? (NSLOT - s0) : CH;
    k_up<64><<<dim3(8, cur), 256, 0, stream>>>(u1, u2, up_w2, up_b2, slot_img, s0);
    k_tail<<<dim3(32, cur), 256, 0, stream>>>(u2, out, tail_w, tail_b, slot_img, s0);
  }
}

// Round 3
// 304.288 us; speedup vs baseline: 4.3514x; 1.4480x over previous
//
#include <hip/hip_runtime.h>

#define EXPN 4
#define CAP 48
#define NSLOT 192   // EXPN*CAP
#define NBLK 4

typedef __attribute__((ext_vector_type(8))) short bf16x8;
typedef __attribute__((ext_vector_type(4))) float f32x4;

static __device__ __forceinline__ float bf2f(unsigned short s) {
  union { unsigned u; float f; } c; c.u = ((unsigned)s) << 16; return c.f;
}
static __device__ __forceinline__ unsigned short f2bf(float f) {
  union { float f; unsigned u; } c; c.f = f;
  unsigned u = c.u;
  return (unsigned short)((u + 0x7fffu + ((u >> 16) & 1u)) >> 16);  // RNE
}
static __device__ __forceinline__ f32x4 mfma16(bf16x8 a, bf16x8 b, f32x4 c) {
  return __builtin_amdgcn_mfma_f32_16x16x32_bf16(a, b, c, 0, 0, 0);
}
static __device__ __forceinline__ float relu_f(float x) { return fmaxf(x, 0.f); }

// ---------------- zero output ----------------
__global__ void k_zero(float4* __restrict__ p, int n4) {
  int i = blockIdx.x * blockDim.x + threadIdx.x;
  int stride = gridDim.x * blockDim.x;
  for (; i < n4; i += stride) p[i] = make_float4(0.f, 0.f, 0.f, 0.f);
}

// ---------------- classifier stage A: conv3->32 + relu + per-band channel sums ----------------
// grid (4 bands, N images), 256 thr. part[n][band][32]
__global__ __launch_bounds__(256) void k_cls_conv(
    const float* __restrict__ x, const float* __restrict__ cw,
    const float* __restrict__ cb, float* __restrict__ part) {
  int n = blockIdx.y, band = blockIdx.x, t = threadIdx.x;
  int og = t >> 6, r = (t >> 3) & 7, cg = t & 7;
  int c0 = cg * 4;
  __shared__ float wl[3 * 32 * 9];
  __shared__ float tile[3 * 10 * 34];
  for (int k = t; k < 864; k += 256) {
    int o = k / 27;
    int rem = k % 27;
    int ci = rem / 9, tap = rem % 9;
    wl[(ci * 32 + o) * 9 + tap] = cw[k];
  }
  const float* inb = x + (size_t)n * 3072;
  for (int k = t; k < 1020; k += 256) {
    int ci = k / 340;
    int rem = k % 340;
    int lr = rem / 34, lc = rem % 34;
    int gr = band * 8 - 1 + lr, gc = lc - 1;
    float v = 0.f;
    if (gr >= 0 && gr < 32 && gc >= 0 && gc < 32) v = inb[(ci * 32 + gr) * 32 + gc];
    tile[k] = v;
  }
  __syncthreads();
  float acc[8][4];
#pragma unroll
  for (int oi = 0; oi < 8; ++oi) {
    float b = cb[og * 8 + oi];
#pragma unroll
    for (int p = 0; p < 4; ++p) acc[oi][p] = b;
  }
#pragma unroll
  for (int ci = 0; ci < 3; ++ci) {
    float iv[3][6];
#pragma unroll
    for (int ky = 0; ky < 3; ++ky)
#pragma unroll
      for (int dx = 0; dx < 6; ++dx)
        iv[ky][dx] = tile[ci * 340 + (r + ky) * 34 + c0 + dx];
#pragma unroll
    for (int oi = 0; oi < 8; ++oi) {
      const float* w9 = &wl[((size_t)ci * 32 + og * 8 + oi) * 9];
#pragma unroll
      for (int ky = 0; ky < 3; ++ky)
#pragma unroll
        for (int kx = 0; kx < 3; ++kx) {
          float wv = w9[ky * 3 + kx];
#pragma unroll
          for (int p = 0; p < 4; ++p) acc[oi][p] += wv * iv[ky][p + kx];
        }
    }
  }
#pragma unroll
  for (int oi = 0; oi < 8; ++oi) {
    float s = relu_f(acc[oi][0]) + relu_f(acc[oi][1]) + relu_f(acc[oi][2]) + relu_f(acc[oi][3]);
#pragma unroll
    for (int off = 32; off >= 1; off >>= 1) s += __shfl_down(s, off, 64);
    if ((t & 63) == 0) part[((size_t)n * 4 + band) * 32 + og * 8 + oi] = s;
  }
}

// ---------------- classifier stage B: band-sum + linear + argmax ----------------
__global__ void k_cls_score(const float* __restrict__ part, const float* __restrict__ fw,
                            const float* __restrict__ fb, int* __restrict__ assign, int N) {
  int n = blockIdx.x * blockDim.x + threadIdx.x;
  if (n >= N) return;
  float cm[32];
#pragma unroll
  for (int o = 0; o < 32; ++o) {
    float s = part[((size_t)n * 4 + 0) * 32 + o] + part[((size_t)n * 4 + 1) * 32 + o] +
              part[((size_t)n * 4 + 2) * 32 + o] + part[((size_t)n * 4 + 3) * 32 + o];
    cm[o] = s * (1.f / 1024.f);
  }
  float best = -1e30f;
  int bi = 0;
  for (int e = 0; e < EXPN; ++e) {
    float sc = fb[e];
#pragma unroll
    for (int o = 0; o < 32; ++o) sc += cm[o] * fw[e * 32 + o];
    if (sc > best) { best = sc; bi = e; }
  }
  assign[n] = bi;
}

// ---------------- routing ----------------
__global__ void k_route(const int* __restrict__ assign, int* __restrict__ slot_img, int N) {
  if (threadIdx.x == 0 && blockIdx.x == 0) {
    int cnt[EXPN];
    for (int e = 0; e < EXPN; ++e) cnt[e] = 0;
    for (int k = 0; k < NSLOT; ++k) slot_img[k] = -1;
    for (int n = 0; n < N; ++n) {
      int e = assign[n];
      if (cnt[e] < CAP) { slot_img[e * CAP + cnt[e]] = n; cnt[e]++; }
    }
  }
}

// ---------------- head: conv 3->32 fp32 VALU, store bf16 channel-last to h and res ----------------
__global__ __launch_bounds__(256) void k_head(
    const float* __restrict__ x, unsigned short* __restrict__ hbuf,
    unsigned short* __restrict__ resbuf, const float* __restrict__ wglob,
    const float* __restrict__ bglob, const int* __restrict__ slot_img) {
  int slot = blockIdx.y;
  int img = slot_img[slot];
  if (img < 0) return;
  int e = slot / CAP;
  int band = blockIdx.x;
  int t = threadIdx.x;
  int og = t >> 6, r = (t >> 3) & 7, cg = t & 7;
  int c0 = cg * 4;
  __shared__ float wl[3 * 32 * 9];
  __shared__ float tile[3 * 10 * 34];
  __shared__ __align__(16) unsigned short ostg[256 * 32];
  const float* wsrc = wglob + (size_t)e * 32 * 27;
  for (int k = t; k < 864; k += 256) {
    int o = k / 27;
    int rem = k % 27;
    int ci = rem / 9, tap = rem % 9;
    wl[(ci * 32 + o) * 9 + tap] = wsrc[k];
  }
  const float* bsrc = bglob + (size_t)e * 32;
  const float* inb = x + (size_t)img * 3072;
  for (int k = t; k < 3 * 10 * 34; k += 256) {
    int ci = k / 340;
    int rem = k % 340;
    int lr = rem / 34, lc = rem % 34;
    int gr = band * 8 - 1 + lr, gc = lc - 1;
    float v = 0.f;
    if (gr >= 0 && gr < 32 && gc >= 0 && gc < 32) v = inb[(ci * 32 + gr) * 32 + gc];
    tile[k] = v;
  }
  __syncthreads();
  float acc[8][4];
#pragma unroll
  for (int oi = 0; oi < 8; ++oi) {
    float b = bsrc[og * 8 + oi];
#pragma unroll
    for (int p = 0; p < 4; ++p) acc[oi][p] = b;
  }
#pragma unroll
  for (int ci = 0; ci < 3; ++ci) {
    float iv[3][6];
#pragma unroll
    for (int ky = 0; ky < 3; ++ky)
#pragma unroll
      for (int dx = 0; dx < 6; ++dx)
        iv[ky][dx] = tile[ci * 340 + (r + ky) * 34 + c0 + dx];
#pragma unroll
    for (int oi = 0; oi < 8; ++oi) {
      const float* w9 = &wl[((size_t)ci * 32 + og * 8 + oi) * 9];
#pragma unroll
      for (int ky = 0; ky < 3; ++ky)
#pragma unroll
        for (int kx = 0; kx < 3; ++kx) {
          float wv = w9[ky * 3 + kx];
#pragma unroll
          for (int p = 0; p < 4; ++p) acc[oi][p] += wv * iv[ky][p + kx];
        }
    }
  }
#pragma unroll
  for (int oi = 0; oi < 8; ++oi)
#pragma unroll
    for (int p = 0; p < 4; ++p)
      ostg[(r * 32 + c0 + p) * 32 + og * 8 + oi] = f2bf(acc[oi][p]);
  __syncthreads();
  for (int u = t; u < 1024; u += 256) {
    int px = u >> 2, c8 = (u & 3) * 8;
    int4 v = *(const int4*)&ostg[px * 32 + c8];
    size_t gi = ((size_t)slot * 1024 + band * 256 + px) * 32 + c8;
    *(int4*)&hbuf[gi] = v;
    *(int4*)&resbuf[gi] = v;
  }
}

// ---------------- MFMA conv 32->32 @32x32, bf16 channel-last ----------------
// MODE 1: out = relu(conv)   MODE 2: out = aux + 0.1*conv   MODE 3: out = conv + aux
template <int MODE>
__global__ __launch_bounds__(256) void k_rb(
    const unsigned short* __restrict__ inbuf, unsigned short* __restrict__ outbuf,
    const unsigned short* __restrict__ aux,
    const float* __restrict__ wglob, const float* __restrict__ bglob,
    int w_estride, int b_estride, const int* __restrict__ slot_img) {
  int slot = blockIdx.y;
  int img = slot_img[slot];
  if (img < 0) return;
  int e = slot / CAP;
  int band = blockIdx.x;  // 0..3
  int t = threadIdx.x;
  int w = t >> 6, l = t & 63;
  int col = l & 15, s4 = l >> 4;
  __shared__ __align__(16) unsigned short tile[4 * 10 * 34 * 8];  // [s][lr][lx][8ch]
  __shared__ __align__(16) unsigned short scr[4 * 16 * 32];       // per-wave [16px][32ch]
  const unsigned short* inb = inbuf + (size_t)slot * 32768;
  for (int u = t; u < 1360; u += 256) {
    int s = u / 340;
    int rem = u - s * 340;
    int lr = rem / 34, lx = rem - lr * 34;
    int gr = band * 8 - 1 + lr, gx = lx - 1;
    int4 v = make_int4(0, 0, 0, 0);
    if (gr >= 0 && gr < 32 && gx >= 0 && gx < 32)
      v = *(const int4*)&inb[(gr * 32 + gx) * 32 + s * 8];
    *(int4*)&tile[u * 8] = v;
  }
  const float* wsrc = wglob + (size_t)e * w_estride;
  const float* bsrc = bglob + (size_t)e * b_estride;
  bf16x8 Bf[9][2];
  float bias[2];
#pragma unroll
  for (int n = 0; n < 2; ++n) {
    int och = n * 16 + col;
    bias[n] = bsrc[och];
#pragma unroll
    for (int tap = 0; tap < 9; ++tap) {
      bf16x8 bb;
#pragma unroll
      for (int j = 0; j < 8; ++j)
        bb[j] = (short)f2bf(wsrc[((size_t)och * 32 + s4 * 8 + j) * 9 + tap]);
      Bf[tap][n] = bb;
    }
  }
  __syncthreads();
  int hs = w >> 1, r0 = (w & 1) * 4;
  f32x4 acc[4][2];
#pragma unroll
  for (int m = 0; m < 4; ++m)
#pragma unroll
    for (int n = 0; n < 2; ++n) acc[m][n] = (f32x4){bias[n], bias[n], bias[n], bias[n]};
  bf16x8 Af[3][3];
#pragma unroll
  for (int ky = 0; ky < 3; ++ky)
#pragma unroll
    for (int kx = 0; kx < 3; ++kx)
      Af[ky][kx] = *(const bf16x8*)&tile[((s4 * 10 + r0 + ky) * 34 + hs * 16 + kx + col) * 8];
#pragma unroll
  for (int r = 0; r < 4; ++r) {
    if (r > 0) {
#pragma unroll
      for (int kx = 0; kx < 3; ++kx)
        Af[(r + 2) % 3][kx] =
            *(const bf16x8*)&tile[((s4 * 10 + r0 + r + 2) * 34 + hs * 16 + kx + col) * 8];
    }
#pragma unroll
    for (int n = 0; n < 2; ++n)
#pragma unroll
      for (int ky = 0; ky < 3; ++ky)
#pragma unroll
        for (int kx = 0; kx < 3; ++kx)
          acc[r][n] = mfma16(Af[(r + ky) % 3][kx], Bf[ky * 3 + kx][n], acc[r][n]);
  }
  unsigned short* wscr = &scr[w * 512];
  unsigned short* outb = outbuf + (size_t)slot * 32768;
  const unsigned short* auxb = (MODE == 1) ? (const unsigned short*)0 : aux + (size_t)slot * 32768;
#pragma unroll
  for (int r = 0; r < 4; ++r) {
#pragma unroll
    for (int n = 0; n < 2; ++n)
#pragma unroll
      for (int reg = 0; reg < 4; ++reg) {
        float v = acc[r][n][reg];
        if (MODE == 1) v = relu_f(v);
        wscr[(s4 * 4 + reg) * 32 + n * 16 + col] = f2bf(v);
      }
    int px2 = l >> 2, c8 = (l & 3) * 8;
    int4 yv = *(const int4*)&wscr[px2 * 32 + c8];
    int grow = band * 8 + r0 + r, gx = hs * 16 + px2;
    size_t gi = ((size_t)grow * 32 + gx) * 32 + c8;
    if (MODE == 2 || MODE == 3) {
      const float sc = (MODE == 2) ? 0.1f : 1.0f;
      int4 av = *(const int4*)&auxb[gi];
      unsigned short* yp = (unsigned short*)&yv;
      unsigned short* ap = (unsigned short*)&av;
#pragma unroll
      for (int j = 0; j < 8; ++j) yp[j] = f2bf(bf2f(ap[j]) + sc * bf2f(yp[j]));
    }
    *(int4*)&outb[gi] = yv;
  }
}

// ---------------- MFMA conv 32->128 + pixel shuffle, bf16 channel-last ----------------
template <int HW>
__global__ __launch_bounds__(256) void k_up(
    const unsigned short* __restrict__ inbuf, unsigned short* __restrict__ outbuf,
    const float* __restrict__ wglob, const float* __restrict__ bglob,
    const int* __restrict__ slot_img, int slot0) {
  int lslot = blockIdx.y;
  int slot = slot0 + lslot;
  int img = slot_img[slot];
  if (img < 0) return;
  int e = slot / CAP;
  int band = blockIdx.x;  // 0..HW/8-1
  int t = threadIdx.x;
  int w = t >> 6, l = t & 63;
  int col = l & 15, s4 = l >> 4;
  constexpr int XP = HW + 2;
  __shared__ __align__(16) unsigned short tile[4 * 10 * XP * 8];
  __shared__ __align__(16) unsigned short scr[4 * 4 * 16 * 8];  // per-wave [ryrx][px][8cc]
  const unsigned short* inb = inbuf + (size_t)slot * 32 * HW * HW;
  for (int u = t; u < 4 * 10 * XP; u += 256) {
    int s = u / (10 * XP);
    int rem = u - s * (10 * XP);
    int lr = rem / XP, lx = rem - lr * XP;
    int gr = band * 8 - 1 + lr, gx = lx - 1;
    int4 v = make_int4(0, 0, 0, 0);
    if (gr >= 0 && gr < HW && gx >= 0 && gx < HW)
      v = *(const int4*)&inb[(gr * HW + gx) * 32 + s * 8];
    *(int4*)&tile[u * 8] = v;
  }
  const float* wsrc = wglob + (size_t)e * 128 * 288;
  const float* bsrc = bglob + (size_t)e * 128;
  bf16x8 Bf[9][2];
  float bias[2];
#pragma unroll
  for (int n = 0; n < 2; ++n) {
    int och = w * 32 + n * 16 + col;
    bias[n] = bsrc[och];
#pragma unroll
    for (int tap = 0; tap < 9; ++tap) {
      bf16x8 bb;
#pragma unroll
      for (int j = 0; j < 8; ++j)
        bb[j] = (short)f2bf(wsrc[((size_t)och * 32 + s4 * 8 + j) * 9 + tap]);
      Bf[tap][n] = bb;
    }
  }
  __syncthreads();
  unsigned short* wscr = &scr[w * 512];
  unsigned short* outb = outbuf + (size_t)(slot - slot0) * (2 * HW) * (2 * HW) * 32;
  for (int h = 0; h < HW / 16; ++h) {
    bf16x8 Af[3][3];
#pragma unroll
    for (int ky = 0; ky < 3; ++ky)
#pragma unroll
      for (int kx = 0; kx < 3; ++kx)
        Af[ky][kx] = *(const bf16x8*)&tile[((s4 * 10 + ky) * XP + h * 16 + kx + col) * 8];
#pragma unroll
    for (int r = 0; r < 8; ++r) {
      if (r > 0) {
#pragma unroll
        for (int kx = 0; kx < 3; ++kx)
          Af[(r + 2) % 3][kx] =
              *(const bf16x8*)&tile[((s4 * 10 + r + 2) * XP + h * 16 + kx + col) * 8];
      }
      f32x4 acc[2];
#pragma unroll
      for (int n = 0; n < 2; ++n) acc[n] = (f32x4){bias[n], bias[n], bias[n], bias[n]};
#pragma unroll
      for (int n = 0; n < 2; ++n)
#pragma unroll
        for (int ky = 0; ky < 3; ++ky)
#pragma unroll
          for (int kx = 0; kx < 3; ++kx)
            acc[n] = mfma16(Af[(r + ky) % 3][kx], Bf[ky * 3 + kx][n], acc[n]);
#pragma unroll
      for (int n = 0; n < 2; ++n) {
        int och = w * 32 + n * 16 + col;
        int ryrx = och & 3, ccl = (och >> 2) & 7;
#pragma unroll
        for (int reg = 0; reg < 4; ++reg)
          wscr[(ryrx * 16 + s4 * 4 + reg) * 8 + ccl] = f2bf(acc[n][reg]);
      }
      int ryrx2 = l >> 4, px2 = l & 15;
      int4 yv = *(const int4*)&wscr[(ryrx2 * 16 + px2) * 8];
      int ry = ryrx2 >> 1, rx = ryrx2 & 1;
      int oy = 2 * (band * 8 + r) + ry, ox = 2 * (h * 16 + px2) + rx;
      size_t oi = ((size_t)oy * (2 * HW) + ox) * 32 + w * 8;
      *(int4*)&outb[oi] = yv;
    }
  }
}

// ---------------- MFMA tail conv 32->3 @128x128, fp32 gather-write ----------------
__global__ __launch_bounds__(256) void k_tail(
    const unsigned short* __restrict__ inbuf, float* __restrict__ out,
    const float* __restrict__ wglob, const float* __restrict__ bglob,
    const int* __restrict__ slot_img, int slot0) {
  int lslot = blockIdx.y;
  int slot = slot0 + lslot;
  int img = slot_img[slot];
  if (img < 0) return;
  int e = slot / CAP;
  int band = blockIdx.x & 15, xh = blockIdx.x >> 4;
  int t = threadIdx.x;
  int w = t >> 6, l = t & 63;
  int col = l & 15, s4 = l >> 4;
  __shared__ __align__(16) unsigned short tile[4 * 10 * 66 * 8];
  const unsigned short* inb = inbuf + (size_t)lslot * 128 * 128 * 32;
  for (int u = t; u < 2640; u += 256) {
    int s = u / 660;
    int rem = u - s * 660;
    int lr = rem / 66, lx = rem - lr * 66;
    int gr = band * 8 - 1 + lr, gx = xh * 64 - 1 + lx;
    int4 v = make_int4(0, 0, 0, 0);
    if (gr >= 0 && gr < 128 && gx >= 0 && gx < 128)
      v = *(const int4*)&inb[(gr * 128 + gx) * 32 + s * 8];
    *(int4*)&tile[u * 8] = v;
  }
  bf16x8 Bf[9];
  float bias = 0.f;
  if (col < 3) bias = bglob[e * 3 + col];
#pragma unroll
  for (int tap = 0; tap < 9; ++tap) {
    bf16x8 bb;
#pragma unroll
    for (int j = 0; j < 8; ++j)
      bb[j] = (col < 3)
                  ? (short)f2bf(wglob[(((size_t)e * 3 + col) * 32 + s4 * 8 + j) * 9 + tap])
                  : (short)0;
    Bf[tap] = bb;
  }
  __syncthreads();
  int hh = w;  // 16-px half within the 64-wide region
  bf16x8 Af[3][3];
#pragma unroll
  for (int ky = 0; ky < 3; ++ky)
#pragma unroll
    for (int kx = 0; kx < 3; ++kx)
      Af[ky][kx] = *(const bf16x8*)&tile[((s4 * 10 + ky) * 66 + hh * 16 + kx + col) * 8];
#pragma unroll
  for (int r = 0; r < 8; ++r) {
    if (r > 0) {
#pragma unroll
      for (int kx = 0; kx < 3; ++kx)
        Af[(r + 2) % 3][kx] =
            *(const bf16x8*)&tile[((s4 * 10 + r + 2) * 66 + hh * 16 + kx + col) * 8];
    }
    f32x4 acc = (f32x4){bias, bias, bias, bias};
#pragma unroll
    for (int ky = 0; ky < 3; ++ky)
#pragma unroll
      for (int kx = 0; kx < 3; ++kx)
        acc = mfma16(Af[(r + ky) % 3][kx], Bf[ky * 3 + kx], acc);
    if (col < 3) {
      int grow = band * 8 + r, gx0 = xh * 64 + hh * 16 + s4 * 4;
      *(float4*)&out[(((size_t)img * 3 + col) * 128 + grow) * 128 + gx0] =
          make_float4(acc[0], acc[1], acc[2], acc[3]);
    }
  }
}

extern "C" void kernel_launch(void* const* d_in, const int* in_sizes, int n_in,
                              void* d_out, int out_size, void* d_ws, size_t ws_size,
                              hipStream_t stream) {
  const float* inputs = (const float*)d_in[0];
  const float* cls_w = (const float*)d_in[1];
  const float* cls_b = (const float*)d_in[2];
  const float* cls_fw = (const float*)d_in[3];
  const float* cls_fb = (const float*)d_in[4];
  const float* head_w = (const float*)d_in[5];
  const float* head_b = (const float*)d_in[6];
  const float* rb_w1 = (const float*)d_in[7];
  const float* rb_b1 = (const float*)d_in[8];
  const float* rb_w2 = (const float*)d_in[9];
  const float* rb_b2 = (const float*)d_in[10];
  const float* end_w = (const float*)d_in[11];
  const float* end_b = (const float*)d_in[12];
  const float* up_w1 = (const float*)d_in[13];
  const float* up_b1 = (const float*)d_in[14];
  const float* up_w2 = (const float*)d_in[15];
  const float* up_b2 = (const float*)d_in[16];
  const float* tail_w = (const float*)d_in[17];
  const float* tail_b = (const float*)d_in[18];
  float* out = (float*)d_out;
  char* ws = (char*)d_ws;

  int N = in_sizes[0] / 3072;  // 128

  int* assign = (int*)ws;
  int* slot_img = (int*)(ws + 512);
  float* part = (float*)(ws + 4096);          // [N][4][32] = 64 KB
  const size_t ABUF = (size_t)NSLOT * 1024 * 32 * 2;   // 12,582,912
  const size_t U1B = (size_t)NSLOT * 64 * 64 * 32 * 2; // 50,331,648
  const size_t SLOT_U2 = (size_t)128 * 128 * 32 * 2;   // 1,048,576
  size_t o_h = 131072;
  unsigned short* h = (unsigned short*)(ws + o_h);
  unsigned short* res = (unsigned short*)(ws + o_h + ABUF);
  unsigned short* tmp = (unsigned short*)(ws + o_h + 2 * ABUF);
  unsigned short* u1 = (unsigned short*)(ws + o_h + 3 * ABUF);
  size_t o_u2full = o_h + 3 * ABUF + U1B;  // ~88 MB

  unsigned short* u2;
  int CH;
  size_t tail_avail = (ws_size > o_u2full) ? (ws_size - o_u2full) : 0;
  int CH_tail = (int)(tail_avail / SLOT_U2);
  const int CH_alias = (int)((3 * ABUF) / SLOT_U2);  // 36 (h/res/tmp dead after up1)
  if (CH_tail >= CH_alias) {
    u2 = (unsigned short*)(ws + o_u2full);
    CH = CH_tail < NSLOT ? CH_tail : NSLOT;
  } else {
    u2 = (unsigned short*)(ws + o_h);
    CH = CH_alias;
  }
  if (CH < 1) CH = 1;

  k_zero<<<2048, 256, 0, stream>>>((float4*)out, out_size / 4);
  k_cls_conv<<<dim3(4, N), 256, 0, stream>>>(inputs, cls_w, cls_b, part);
  k_cls_score<<<(N + 63) / 64, 64, 0, stream>>>(part, cls_fw, cls_fb, assign, N);
  k_route<<<1, 64, 0, stream>>>(assign, slot_img, N);

  k_head<<<dim3(4, NSLOT), 256, 0, stream>>>(inputs, h, res, head_w, head_b, slot_img);

  for (int i = 0; i < NBLK; ++i) {
    k_rb<1><<<dim3(4, NSLOT), 256, 0, stream>>>(
        res, tmp, (const unsigned short*)0, rb_w1 + (size_t)i * 9216, rb_b1 + i * 32,
        NBLK * 9216, NBLK * 32, slot_img);
    k_rb<2><<<dim3(4, NSLOT), 256, 0, stream>>>(
        tmp, res, res, rb_w2 + (size_t)i * 9216, rb_b2 + i * 32,
        NBLK * 9216, NBLK * 32, slot_img);
  }

  k_rb<3><<<dim3(4, NSLOT), 256, 0, stream>>>(
      res, tmp, h, end_w, end_b, 9216, 32, slot_img);

  k_up<32><<<dim3(4, NSLOT), 256, 0, stream>>>(tmp, u1, up_w1, up_b1, slot_img, 0);

  for (int s0 = 0; s0 < NSLOT; s0 += CH) {
    int cur = (NSLOT - s0) < CH ? (NSLOT - s0) : CH;
    k_up<64><<<dim3(8, cur), 256, 0, stream>>>(u1, u2, up_w2, up_b2, slot_img, s0);
    k_tail<<<dim3(32, cur), 256, 0, stream>>>(u2, out, tail_w, tail_b, slot_img, s0);
  }
}

// Round 4
// 265.357 us; speedup vs baseline: 4.9898x; 1.1467x over previous
//
#include <hip/hip_runtime.h>

#define EXPN 4
#define CAP 48
#define NSLOT 192   // EXPN*CAP
#define NBLK 4

typedef __attribute__((ext_vector_type(8))) short bf16x8;
typedef __attribute__((ext_vector_type(4))) float f32x4;

static __device__ __forceinline__ float bf2f(unsigned short s) {
  union { unsigned u; float f; } c; c.u = ((unsigned)s) << 16; return c.f;
}
static __device__ __forceinline__ unsigned short f2bf(float f) {
  union { float f; unsigned u; } c; c.f = f;
  unsigned u = c.u;
  return (unsigned short)((u + 0x7fffu + ((u >> 16) & 1u)) >> 16);  // RNE
}
static __device__ __forceinline__ f32x4 mfma16(bf16x8 a, bf16x8 b, f32x4 c) {
  return __builtin_amdgcn_mfma_f32_16x16x32_bf16(a, b, c, 0, 0, 0);
}
static __device__ __forceinline__ float relu_f(float x) { return fmaxf(x, 0.f); }

// ---------------- zero output ----------------
__global__ void k_zero(float4* __restrict__ p, int n4) {
  int i = blockIdx.x * blockDim.x + threadIdx.x;
  int stride = gridDim.x * blockDim.x;
  for (; i < n4; i += stride) p[i] = make_float4(0.f, 0.f, 0.f, 0.f);
}

// ---------------- classifier stage A ----------------
__global__ __launch_bounds__(256) void k_cls_conv(
    const float* __restrict__ x, const float* __restrict__ cw,
    const float* __restrict__ cb, float* __restrict__ part) {
  int n = blockIdx.y, band = blockIdx.x, t = threadIdx.x;
  int og = t >> 6, r = (t >> 3) & 7, cg = t & 7;
  int c0 = cg * 4;
  __shared__ float wl[3 * 32 * 9];
  __shared__ float tile[3 * 10 * 34];
  for (int k = t; k < 864; k += 256) {
    int o = k / 27;
    int rem = k % 27;
    int ci = rem / 9, tap = rem % 9;
    wl[(ci * 32 + o) * 9 + tap] = cw[k];
  }
  const float* inb = x + (size_t)n * 3072;
  for (int k = t; k < 1020; k += 256) {
    int ci = k / 340;
    int rem = k % 340;
    int lr = rem / 34, lc = rem % 34;
    int gr = band * 8 - 1 + lr, gc = lc - 1;
    float v = 0.f;
    if (gr >= 0 && gr < 32 && gc >= 0 && gc < 32) v = inb[(ci * 32 + gr) * 32 + gc];
    tile[k] = v;
  }
  __syncthreads();
  float acc[8][4];
#pragma unroll
  for (int oi = 0; oi < 8; ++oi) {
    float b = cb[og * 8 + oi];
#pragma unroll
    for (int p = 0; p < 4; ++p) acc[oi][p] = b;
  }
#pragma unroll
  for (int ci = 0; ci < 3; ++ci) {
    float iv[3][6];
#pragma unroll
    for (int ky = 0; ky < 3; ++ky)
#pragma unroll
      for (int dx = 0; dx < 6; ++dx)
        iv[ky][dx] = tile[ci * 340 + (r + ky) * 34 + c0 + dx];
#pragma unroll
    for (int oi = 0; oi < 8; ++oi) {
      const float* w9 = &wl[((size_t)ci * 32 + og * 8 + oi) * 9];
#pragma unroll
      for (int ky = 0; ky < 3; ++ky)
#pragma unroll
        for (int kx = 0; kx < 3; ++kx) {
          float wv = w9[ky * 3 + kx];
#pragma unroll
          for (int p = 0; p < 4; ++p) acc[oi][p] += wv * iv[ky][p + kx];
        }
    }
  }
#pragma unroll
  for (int oi = 0; oi < 8; ++oi) {
    float s = relu_f(acc[oi][0]) + relu_f(acc[oi][1]) + relu_f(acc[oi][2]) + relu_f(acc[oi][3]);
#pragma unroll
    for (int off = 32; off >= 1; off >>= 1) s += __shfl_down(s, off, 64);
    if ((t & 63) == 0) part[((size_t)n * 4 + band) * 32 + og * 8 + oi] = s;
  }
}

// ---------------- classifier stage B ----------------
__global__ void k_cls_score(const float* __restrict__ part, const float* __restrict__ fw,
                            const float* __restrict__ fb, int* __restrict__ assign, int N) {
  int n = blockIdx.x * blockDim.x + threadIdx.x;
  if (n >= N) return;
  float cm[32];
#pragma unroll
  for (int o = 0; o < 32; ++o) {
    float s = part[((size_t)n * 4 + 0) * 32 + o] + part[((size_t)n * 4 + 1) * 32 + o] +
              part[((size_t)n * 4 + 2) * 32 + o] + part[((size_t)n * 4 + 3) * 32 + o];
    cm[o] = s * (1.f / 1024.f);
  }
  float best = -1e30f;
  int bi = 0;
  for (int e = 0; e < EXPN; ++e) {
    float sc = fb[e];
#pragma unroll
    for (int o = 0; o < 32; ++o) sc += cm[o] * fw[e * 32 + o];
    if (sc > best) { best = sc; bi = e; }
  }
  assign[n] = bi;
}

// ---------------- routing ----------------
__global__ void k_route(const int* __restrict__ assign, int* __restrict__ slot_img, int N) {
  if (threadIdx.x == 0 && blockIdx.x == 0) {
    int cnt[EXPN];
    for (int e = 0; e < EXPN; ++e) cnt[e] = 0;
    for (int k = 0; k < NSLOT; ++k) slot_img[k] = -1;
    for (int n = 0; n < N; ++n) {
      int e = assign[n];
      if (cnt[e] < CAP) { slot_img[e * CAP + cnt[e]] = n; cnt[e]++; }
    }
  }
}

// ---------------- head: conv 3->32 fp32 VALU, store bf16 channel-last to h ----------------
__global__ __launch_bounds__(256) void k_head(
    const float* __restrict__ x, unsigned short* __restrict__ hbuf,
    const float* __restrict__ wglob, const float* __restrict__ bglob,
    const int* __restrict__ slot_img) {
  int slot = blockIdx.y;
  int img = slot_img[slot];
  if (img < 0) return;
  int e = slot / CAP;
  int band = blockIdx.x;
  int t = threadIdx.x;
  int og = t >> 6, r = (t >> 3) & 7, cg = t & 7;
  int c0 = cg * 4;
  __shared__ float wl[3 * 32 * 9];
  __shared__ float tile[3 * 10 * 34];
  __shared__ __align__(16) unsigned short ostg[256 * 32];
  const float* wsrc = wglob + (size_t)e * 32 * 27;
  for (int k = t; k < 864; k += 256) {
    int o = k / 27;
    int rem = k % 27;
    int ci = rem / 9, tap = rem % 9;
    wl[(ci * 32 + o) * 9 + tap] = wsrc[k];
  }
  const float* bsrc = bglob + (size_t)e * 32;
  const float* inb = x + (size_t)img * 3072;
  for (int k = t; k < 3 * 10 * 34; k += 256) {
    int ci = k / 340;
    int rem = k % 340;
    int lr = rem / 34, lc = rem % 34;
    int gr = band * 8 - 1 + lr, gc = lc - 1;
    float v = 0.f;
    if (gr >= 0 && gr < 32 && gc >= 0 && gc < 32) v = inb[(ci * 32 + gr) * 32 + gc];
    tile[k] = v;
  }
  __syncthreads();
  float acc[8][4];
#pragma unroll
  for (int oi = 0; oi < 8; ++oi) {
    float b = bsrc[og * 8 + oi];
#pragma unroll
    for (int p = 0; p < 4; ++p) acc[oi][p] = b;
  }
#pragma unroll
  for (int ci = 0; ci < 3; ++ci) {
    float iv[3][6];
#pragma unroll
    for (int ky = 0; ky < 3; ++ky)
#pragma unroll
      for (int dx = 0; dx < 6; ++dx)
        iv[ky][dx] = tile[ci * 340 + (r + ky) * 34 + c0 + dx];
#pragma unroll
    for (int oi = 0; oi < 8; ++oi) {
      const float* w9 = &wl[((size_t)ci * 32 + og * 8 + oi) * 9];
#pragma unroll
      for (int ky = 0; ky < 3; ++ky)
#pragma unroll
        for (int kx = 0; kx < 3; ++kx) {
          float wv = w9[ky * 3 + kx];
#pragma unroll
          for (int p = 0; p < 4; ++p) acc[oi][p] += wv * iv[ky][p + kx];
        }
    }
  }
#pragma unroll
  for (int oi = 0; oi < 8; ++oi)
#pragma unroll
    for (int p = 0; p < 4; ++p)
      ostg[(r * 32 + c0 + p) * 32 + og * 8 + oi] = f2bf(acc[oi][p]);
  __syncthreads();
  for (int u = t; u < 1024; u += 256) {
    int px = u >> 2, c8 = (u & 3) * 8;
    int4 v = *(const int4*)&ostg[px * 32 + c8];
    size_t gi = ((size_t)slot * 1024 + band * 256 + px) * 32 + c8;
    *(int4*)&hbuf[gi] = v;
  }
}

// ---------------- body mega-kernel: 4 ResBlocks + end(+h) + up1, all in LDS ----------------
// EPI 0: t = relu(y) -> dstP ; EPI 1: dstP[px] += 0.1*y (rmw) ; EPI 2: y + h -> dstP
template <int EPI>
static __device__ __forceinline__ void conv32_lds(
    const unsigned short* __restrict__ srcP, unsigned short* __restrict__ dstP,
    const unsigned short* __restrict__ hb, unsigned short* __restrict__ wscr,
    const float* __restrict__ wsrc, const float* __restrict__ bsrc,
    int w, int l, int col, int s4) {
  bf16x8 Bf[9][2];
  float bias[2];
#pragma unroll
  for (int n = 0; n < 2; ++n) {
    int och = n * 16 + col;
    bias[n] = bsrc[och];
#pragma unroll
    for (int tap = 0; tap < 9; ++tap) {
      bf16x8 bb;
#pragma unroll
      for (int j = 0; j < 8; ++j)
        bb[j] = (short)f2bf(wsrc[((size_t)och * 32 + s4 * 8 + j) * 9 + tap]);
      Bf[tap][n] = bb;
    }
  }
#pragma unroll
  for (int xh = 0; xh < 2; ++xh) {
    int x0 = xh * 16;
#pragma unroll
    for (int rg = 0; rg < 2; ++rg) {
      int rbase = w * 8 + rg * 4;
      f32x4 acc[4][2];
#pragma unroll
      for (int m = 0; m < 4; ++m)
#pragma unroll
        for (int n = 0; n < 2; ++n) acc[m][n] = (f32x4){bias[n], bias[n], bias[n], bias[n]};
      bf16x8 Af[3][3];
#pragma unroll
      for (int ky = 0; ky < 3; ++ky)
#pragma unroll
        for (int kx = 0; kx < 3; ++kx)
          Af[ky][kx] = *(const bf16x8*)&srcP[(((rbase + ky) * 34) + x0 + col + kx) * 32 + s4 * 8];
#pragma unroll
      for (int r = 0; r < 4; ++r) {
        if (r > 0) {
#pragma unroll
          for (int kx = 0; kx < 3; ++kx)
            Af[(r + 2) % 3][kx] =
                *(const bf16x8*)&srcP[(((rbase + r + 2) * 34) + x0 + col + kx) * 32 + s4 * 8];
        }
#pragma unroll
        for (int n = 0; n < 2; ++n)
#pragma unroll
          for (int ky = 0; ky < 3; ++ky)
#pragma unroll
            for (int kx = 0; kx < 3; ++kx)
              acc[r][n] = mfma16(Af[(r + ky) % 3][kx], Bf[ky * 3 + kx][n], acc[r][n]);
      }
      // epilogue: 4 rows
#pragma unroll
      for (int r = 0; r < 4; ++r) {
        int row = rbase + r;
#pragma unroll
        for (int n = 0; n < 2; ++n)
#pragma unroll
          for (int reg = 0; reg < 4; ++reg) {
            float v = acc[r][n][reg];
            if (EPI == 0) v = relu_f(v);
            wscr[(s4 * 4 + reg) * 32 + n * 16 + col] = f2bf(v);
          }
        int px2 = l >> 2, c8 = (l & 3) * 8;
        int4 yv = *(const int4*)&wscr[px2 * 32 + c8];
        int x = x0 + px2;
        unsigned li = (unsigned)(((row + 1) * 34 + (x + 1)) * 32 + c8);
        if (EPI == 1) {
          int4 rv = *(const int4*)&dstP[li];
          unsigned short* yp = (unsigned short*)&yv;
          unsigned short* rp = (unsigned short*)&rv;
#pragma unroll
          for (int j = 0; j < 8; ++j) yp[j] = f2bf(bf2f(rp[j]) + 0.1f * bf2f(yp[j]));
          *(int4*)&dstP[li] = yv;
        } else if (EPI == 2) {
          int4 hv = *(const int4*)&hb[((size_t)row * 32 + x) * 32 + c8];
          unsigned short* yp = (unsigned short*)&yv;
          unsigned short* hp = (unsigned short*)&hv;
#pragma unroll
          for (int j = 0; j < 8; ++j) yp[j] = f2bf(bf2f(hp[j]) + bf2f(yp[j]));
          *(int4*)&dstP[li] = yv;
        } else {
          *(int4*)&dstP[li] = yv;
        }
      }
    }
  }
}

__global__ __launch_bounds__(256, 1) void k_body(
    const unsigned short* __restrict__ hbuf, unsigned short* __restrict__ u1,
    const float* __restrict__ rb_w1, const float* __restrict__ rb_b1,
    const float* __restrict__ rb_w2, const float* __restrict__ rb_b2,
    const float* __restrict__ end_w, const float* __restrict__ end_b,
    const float* __restrict__ up_w1, const float* __restrict__ up_b1,
    const int* __restrict__ slot_img) {
  int slot = blockIdx.x;
  int img = slot_img[slot];
  if (img < 0) return;
  int e = slot / CAP;
  int t = threadIdx.x;
  int w = t >> 6, l = t & 63;
  int col = l & 15, s4 = l >> 4;

  __shared__ __align__(16) unsigned short resP[34 * 34 * 32];  // 73,984 B
  __shared__ __align__(16) unsigned short tP[34 * 34 * 32];    // 73,984 B
  __shared__ __align__(16) unsigned short scr[4 * 512];        // 4 KB

  // zero both padded buffers
  int4 z = make_int4(0, 0, 0, 0);
  for (int u = t; u < 4624; u += 256) {
    *(int4*)&resP[u * 8] = z;
    *(int4*)&tP[u * 8] = z;
  }
  __syncthreads();
  // stage head output (res) into padded interior
  const unsigned short* hsl = hbuf + (size_t)slot * 32768;
  for (int u = t; u < 4096; u += 256) {
    int px = u >> 2, c8 = (u & 3) * 8;
    *(int4*)&resP[(((px >> 5) + 1) * 34 + (px & 31) + 1) * 32 + c8] =
        *(const int4*)&hsl[px * 32 + c8];
  }
  __syncthreads();

  unsigned short* wscr = &scr[w * 512];

  for (int i = 0; i < NBLK; ++i) {
    conv32_lds<0>(resP, tP, nullptr, wscr,
                  rb_w1 + (size_t)e * NBLK * 9216 + (size_t)i * 9216,
                  rb_b1 + (size_t)e * NBLK * 32 + i * 32, w, l, col, s4);
    __syncthreads();
    conv32_lds<1>(tP, resP, nullptr, wscr,
                  rb_w2 + (size_t)e * NBLK * 9216 + (size_t)i * 9216,
                  rb_b2 + (size_t)e * NBLK * 32 + i * 32, w, l, col, s4);
    __syncthreads();
  }
  // end conv + h skip -> tP
  conv32_lds<2>(resP, tP, hsl, wscr, end_w + (size_t)e * 9216, end_b + (size_t)e * 32,
                w, l, col, s4);
  __syncthreads();

  // up1: conv 32->128 + pixel shuffle, write u1 [slot][64][64][32]
  {
    const float* wsrc = up_w1 + (size_t)e * 128 * 288;
    const float* bsrc = up_b1 + (size_t)e * 128;
    bf16x8 Bf[9][2];
    float bias[2];
#pragma unroll
    for (int n = 0; n < 2; ++n) {
      int och = w * 32 + n * 16 + col;
      bias[n] = bsrc[och];
#pragma unroll
      for (int tap = 0; tap < 9; ++tap) {
        bf16x8 bb;
#pragma unroll
        for (int j = 0; j < 8; ++j)
          bb[j] = (short)f2bf(wsrc[((size_t)och * 32 + s4 * 8 + j) * 9 + tap]);
        Bf[tap][n] = bb;
      }
    }
    unsigned short* u1g = u1 + (size_t)slot * 64 * 64 * 32;
#pragma unroll
    for (int xh = 0; xh < 2; ++xh) {
      int x0 = xh * 16;
      for (int rg = 0; rg < 8; ++rg) {
        int rbase = rg * 4;
        f32x4 acc[4][2];
#pragma unroll
        for (int m = 0; m < 4; ++m)
#pragma unroll
          for (int n = 0; n < 2; ++n) acc[m][n] = (f32x4){bias[n], bias[n], bias[n], bias[n]};
        bf16x8 Af[3][3];
#pragma unroll
        for (int ky = 0; ky < 3; ++ky)
#pragma unroll
          for (int kx = 0; kx < 3; ++kx)
            Af[ky][kx] = *(const bf16x8*)&tP[(((rbase + ky) * 34) + x0 + col + kx) * 32 + s4 * 8];
#pragma unroll
        for (int r = 0; r < 4; ++r) {
          if (r > 0) {
#pragma unroll
            for (int kx = 0; kx < 3; ++kx)
              Af[(r + 2) % 3][kx] =
                  *(const bf16x8*)&tP[(((rbase + r + 2) * 34) + x0 + col + kx) * 32 + s4 * 8];
          }
#pragma unroll
          for (int n = 0; n < 2; ++n)
#pragma unroll
            for (int ky = 0; ky < 3; ++ky)
#pragma unroll
              for (int kx = 0; kx < 3; ++kx)
                acc[r][n] = mfma16(Af[(r + ky) % 3][kx], Bf[ky * 3 + kx][n], acc[r][n]);
        }
#pragma unroll
        for (int r = 0; r < 4; ++r) {
          int row = rbase + r;
#pragma unroll
          for (int n = 0; n < 2; ++n) {
            int och = w * 32 + n * 16 + col;
            int ryrx = och & 3, ccl = (och >> 2) & 7;
#pragma unroll
            for (int reg = 0; reg < 4; ++reg)
              wscr[(ryrx * 16 + s4 * 4 + reg) * 8 + ccl] = f2bf(acc[r][n][reg]);
          }
          int ryrx2 = l >> 4, px2 = l & 15;
          int4 yv = *(const int4*)&wscr[(ryrx2 * 16 + px2) * 8];
          int ry = ryrx2 >> 1, rx = ryrx2 & 1;
          int oy = 2 * row + ry, ox = 2 * (x0 + px2) + rx;
          *(int4*)&u1g[((size_t)oy * 64 + ox) * 32 + w * 8] = yv;
        }
      }
    }
  }
}

// ---------------- MFMA conv 32->128 + pixel shuffle (up2), bf16 channel-last ----------------
template <int HW>
__global__ __launch_bounds__(256) void k_up(
    const unsigned short* __restrict__ inbuf, unsigned short* __restrict__ outbuf,
    const float* __restrict__ wglob, const float* __restrict__ bglob,
    const int* __restrict__ slot_img, int slot0) {
  int lslot = blockIdx.y;
  int slot = slot0 + lslot;
  int img = slot_img[slot];
  if (img < 0) return;
  int e = slot / CAP;
  int band = blockIdx.x;
  int t = threadIdx.x;
  int w = t >> 6, l = t & 63;
  int col = l & 15, s4 = l >> 4;
  constexpr int XP = HW + 2;
  __shared__ __align__(16) unsigned short tile[4 * 10 * XP * 8];
  __shared__ __align__(16) unsigned short scr[4 * 4 * 16 * 8];
  const unsigned short* inb = inbuf + (size_t)slot * 32 * HW * HW;
  for (int u = t; u < 4 * 10 * XP; u += 256) {
    int s = u / (10 * XP);
    int rem = u - s * (10 * XP);
    int lr = rem / XP, lx = rem - lr * XP;
    int gr = band * 8 - 1 + lr, gx = lx - 1;
    int4 v = make_int4(0, 0, 0, 0);
    if (gr >= 0 && gr < HW && gx >= 0 && gx < HW)
      v = *(const int4*)&inb[(gr * HW + gx) * 32 + s * 8];
    *(int4*)&tile[u * 8] = v;
  }
  const float* wsrc = wglob + (size_t)e * 128 * 288;
  const float* bsrc = bglob + (size_t)e * 128;
  bf16x8 Bf[9][2];
  float bias[2];
#pragma unroll
  for (int n = 0; n < 2; ++n) {
    int och = w * 32 + n * 16 + col;
    bias[n] = bsrc[och];
#pragma unroll
    for (int tap = 0; tap < 9; ++tap) {
      bf16x8 bb;
#pragma unroll
      for (int j = 0; j < 8; ++j)
        bb[j] = (short)f2bf(wsrc[((size_t)och * 32 + s4 * 8 + j) * 9 + tap]);
      Bf[tap][n] = bb;
    }
  }
  __syncthreads();
  unsigned short* wscr = &scr[w * 512];
  unsigned short* outb = outbuf + (size_t)(slot - slot0) * (2 * HW) * (2 * HW) * 32;
  for (int h = 0; h < HW / 16; ++h) {
    bf16x8 Af[3][3];
#pragma unroll
    for (int ky = 0; ky < 3; ++ky)
#pragma unroll
      for (int kx = 0; kx < 3; ++kx)
        Af[ky][kx] = *(const bf16x8*)&tile[((s4 * 10 + ky) * XP + h * 16 + kx + col) * 8];
#pragma unroll
    for (int r = 0; r < 8; ++r) {
      if (r > 0) {
#pragma unroll
        for (int kx = 0; kx < 3; ++kx)
          Af[(r + 2) % 3][kx] =
              *(const bf16x8*)&tile[((s4 * 10 + r + 2) * XP + h * 16 + kx + col) * 8];
      }
      f32x4 acc[2];
#pragma unroll
      for (int n = 0; n < 2; ++n) acc[n] = (f32x4){bias[n], bias[n], bias[n], bias[n]};
#pragma unroll
      for (int n = 0; n < 2; ++n)
#pragma unroll
        for (int ky = 0; ky < 3; ++ky)
#pragma unroll
          for (int kx = 0; kx < 3; ++kx)
            acc[n] = mfma16(Af[(r + ky) % 3][kx], Bf[ky * 3 + kx][n], acc[n]);
#pragma unroll
      for (int n = 0; n < 2; ++n) {
        int och = w * 32 + n * 16 + col;
        int ryrx = och & 3, ccl = (och >> 2) & 7;
#pragma unroll
        for (int reg = 0; reg < 4; ++reg)
          wscr[(ryrx * 16 + s4 * 4 + reg) * 8 + ccl] = f2bf(acc[n][reg]);
      }
      int ryrx2 = l >> 4, px2 = l & 15;
      int4 yv = *(const int4*)&wscr[(ryrx2 * 16 + px2) * 8];
      int ry = ryrx2 >> 1, rx = ryrx2 & 1;
      int oy = 2 * (band * 8 + r) + ry, ox = 2 * (h * 16 + px2) + rx;
      size_t oi = ((size_t)oy * (2 * HW) + ox) * 32 + w * 8;
      *(int4*)&outb[oi] = yv;
    }
  }
}

// ---------------- MFMA tail conv 32->3 @128x128, fp32 gather-write ----------------
__global__ __launch_bounds__(256) void k_tail(
    const unsigned short* __restrict__ inbuf, float* __restrict__ out,
    const float* __restrict__ wglob, const float* __restrict__ bglob,
    const int* __restrict__ slot_img, int slot0) {
  int lslot = blockIdx.y;
  int slot = slot0 + lslot;
  int img = slot_img[slot];
  if (img < 0) return;
  int e = slot / CAP;
  int band = blockIdx.x & 15, xh = blockIdx.x >> 4;
  int t = threadIdx.x;
  int w = t >> 6, l = t & 63;
  int col = l & 15, s4 = l >> 4;
  __shared__ __align__(16) unsigned short tile[4 * 10 * 66 * 8];
  const unsigned short* inb = inbuf + (size_t)lslot * 128 * 128 * 32;
  for (int u = t; u < 2640; u += 256) {
    int s = u / 660;
    int rem = u - s * 660;
    int lr = rem / 66, lx = rem - lr * 66;
    int gr = band * 8 - 1 + lr, gx = xh * 64 - 1 + lx;
    int4 v = make_int4(0, 0, 0, 0);
    if (gr >= 0 && gr < 128 && gx >= 0 && gx < 128)
      v = *(const int4*)&inb[(gr * 128 + gx) * 32 + s * 8];
    *(int4*)&tile[u * 8] = v;
  }
  bf16x8 Bf[9];
  float bias = 0.f;
  if (col < 3) bias = bglob[e * 3 + col];
#pragma unroll
  for (int tap = 0; tap < 9; ++tap) {
    bf16x8 bb;
#pragma unroll
    for (int j = 0; j < 8; ++j)
      bb[j] = (col < 3)
                  ? (short)f2bf(wglob[(((size_t)e * 3 + col) * 32 + s4 * 8 + j) * 9 + tap])
                  : (short)0;
    Bf[tap] = bb;
  }
  __syncthreads();
  int hh = w;
  bf16x8 Af[3][3];
#pragma unroll
  for (int ky = 0; ky < 3; ++ky)
#pragma unroll
    for (int kx = 0; kx < 3; ++kx)
      Af[ky][kx] = *(const bf16x8*)&tile[((s4 * 10 + ky) * 66 + hh * 16 + kx + col) * 8];
#pragma unroll
  for (int r = 0; r < 8; ++r) {
    if (r > 0) {
#pragma unroll
      for (int kx = 0; kx < 3; ++kx)
        Af[(r + 2) % 3][kx] =
            *(const bf16x8*)&tile[((s4 * 10 + r + 2) * 66 + hh * 16 + kx + col) * 8];
    }
    f32x4 acc = (f32x4){bias, bias, bias, bias};
#pragma unroll
    for (int ky = 0; ky < 3; ++ky)
#pragma unroll
      for (int kx = 0; kx < 3; ++kx)
        acc = mfma16(Af[(r + ky) % 3][kx], Bf[ky * 3 + kx], acc);
    if (col < 3) {
      int grow = band * 8 + r, gx0 = xh * 64 + hh * 16 + s4 * 4;
      *(float4*)&out[(((size_t)img * 3 + col) * 128 + grow) * 128 + gx0] =
          make_float4(acc[0], acc[1], acc[2], acc[3]);
    }
  }
}

extern "C" void kernel_launch(void* const* d_in, const int* in_sizes, int n_in,
                              void* d_out, int out_size, void* d_ws, size_t ws_size,
                              hipStream_t stream) {
  const float* inputs = (const float*)d_in[0];
  const float* cls_w = (const float*)d_in[1];
  const float* cls_b = (const float*)d_in[2];
  const float* cls_fw = (const float*)d_in[3];
  const float* cls_fb = (const float*)d_in[4];
  const float* head_w = (const float*)d_in[5];
  const float* head_b = (const float*)d_in[6];
  const float* rb_w1 = (const float*)d_in[7];
  const float* rb_b1 = (const float*)d_in[8];
  const float* rb_w2 = (const float*)d_in[9];
  const float* rb_b2 = (const float*)d_in[10];
  const float* end_w = (const float*)d_in[11];
  const float* end_b = (const float*)d_in[12];
  const float* up_w1 = (const float*)d_in[13];
  const float* up_b1 = (const float*)d_in[14];
  const float* up_w2 = (const float*)d_in[15];
  const float* up_b2 = (const float*)d_in[16];
  const float* tail_w = (const float*)d_in[17];
  const float* tail_b = (const float*)d_in[18];
  float* out = (float*)d_out;
  char* ws = (char*)d_ws;

  int N = in_sizes[0] / 3072;  // 128

  int* assign = (int*)ws;
  int* slot_img = (int*)(ws + 512);
  float* part = (float*)(ws + 4096);                    // [N][4][32]
  const size_t ABUF = (size_t)NSLOT * 1024 * 32 * 2;    // 12,582,912
  const size_t U1B = (size_t)NSLOT * 64 * 64 * 32 * 2;  // 50,331,648
  const size_t SLOT_U2 = (size_t)128 * 128 * 32 * 2;    // 1,048,576
  size_t o_h = 131072;
  unsigned short* h = (unsigned short*)(ws + o_h);
  unsigned short* u1 = (unsigned short*)(ws + o_h + ABUF);
  size_t o_u2full = o_h + ABUF + U1B;  // ~63 MB

  unsigned short* u2;
  int CH;
  size_t tail_avail = (ws_size > o_u2full) ? (ws_size - o_u2full) : 0;
  int CH_tail = (int)(tail_avail / SLOT_U2);
  const int CH_alias = (int)(ABUF / SLOT_U2);  // 12 (h dead after body)
  if (CH_tail >= CH_alias) {
    u2 = (unsigned short*)(ws + o_u2full);
    CH = CH_tail < NSLOT ? CH_tail : NSLOT;
  } else {
    u2 = (unsigned short*)(ws + o_h);
    CH = CH_alias;
  }
  if (CH < 1) CH = 1;

  k_zero<<<2048, 256, 0, stream>>>((float4*)out, out_size / 4);
  k_cls_conv<<<dim3(4, N), 256, 0, stream>>>(inputs, cls_w, cls_b, part);
  k_cls_score<<<(N + 63) / 64, 64, 0, stream>>>(part, cls_fw, cls_fb, assign, N);
  k_route<<<1, 64, 0, stream>>>(assign, slot_img, N);

  k_head<<<dim3(4, NSLOT), 256, 0, stream>>>(inputs, h, head_w, head_b, slot_img);

  k_body<<<NSLOT, 256, 0, stream>>>(h, u1, rb_w1, rb_b1, rb_w2, rb_b2, end_w, end_b,
                                    up_w1, up_b1, slot_img);

  for (int s0 = 0; s0 < NSLOT; s0 += CH) {
    int cur = (NSLOT - s0) < CH ? (NSLOT - s0) : CH;
    k_up<64><<<dim3(8, cur), 256, 0, stream>>>(u1, u2, up_w2, up_b2, slot_img, s0);
    k_tail<<<dim3(32, cur), 256, 0, stream>>>(u2, out, tail_w, tail_b, slot_img, s0);
  }
}

// Round 5
// 199.623 us; speedup vs baseline: 6.6329x; 1.3293x over previous
//
#include <hip/hip_runtime.h>

#define EXPN 4
#define CAP 48
#define NSLOT 192   // EXPN*CAP
#define NBLK 4

// transformed-weight layout (bf16), per expert:
#define OFF_RB1 0         // + i*9216
#define OFF_RB2 36864     // + i*9216
#define OFF_END 73728
#define OFF_UP1 82944
#define OFF_UP2 119808
#define OFF_TAIL 156672
#define PER_E 157536

typedef __attribute__((ext_vector_type(8))) short bf16x8;
typedef __attribute__((ext_vector_type(4))) float f32x4;

static __device__ __forceinline__ float bf2f(unsigned short s) {
  union { unsigned u; float f; } c; c.u = ((unsigned)s) << 16; return c.f;
}
static __device__ __forceinline__ unsigned short f2bf(float f) {
  union { float f; unsigned u; } c; c.f = f;
  unsigned u = c.u;
  return (unsigned short)((u + 0x7fffu + ((u >> 16) & 1u)) >> 16);  // RNE
}
static __device__ __forceinline__ f32x4 mfma16(bf16x8 a, bf16x8 b, f32x4 c) {
  return __builtin_amdgcn_mfma_f32_16x16x32_bf16(a, b, c, 0, 0, 0);
}
static __device__ __forceinline__ float relu_f(float x) { return fmaxf(x, 0.f); }

// ---------------- zero output ----------------
__global__ void k_zero(float4* __restrict__ p, int n4) {
  int i = blockIdx.x * blockDim.x + threadIdx.x;
  int stride = gridDim.x * blockDim.x;
  for (; i < n4; i += stride) p[i] = make_float4(0.f, 0.f, 0.f, 0.f);
}

// ---------------- weight transform: fp32 [och][ich][3][3] -> bf16 [tap][och][ich] ----------------
__global__ __launch_bounds__(256) void k_wxform(
    const float* __restrict__ rb_w1, const float* __restrict__ rb_w2,
    const float* __restrict__ end_w, const float* __restrict__ up_w1,
    const float* __restrict__ up_w2, const float* __restrict__ tail_w,
    unsigned short* __restrict__ wt) {
  int idx = blockIdx.x * 256 + threadIdx.x;
  if (idx >= EXPN * PER_E) return;
  int e = idx / PER_E, r = idx % PER_E;
  const float* src;
  int c, OC;
  if (r < OFF_RB2) {
    int i = r / 9216; c = r % 9216; OC = 32;
    src = rb_w1 + ((size_t)e * NBLK + i) * 9216;
  } else if (r < OFF_END) {
    int i = (r - OFF_RB2) / 9216; c = (r - OFF_RB2) % 9216; OC = 32;
    src = rb_w2 + ((size_t)e * NBLK + i) * 9216;
  } else if (r < OFF_UP1) {
    c = r - OFF_END; OC = 32;
    src = end_w + (size_t)e * 9216;
  } else if (r < OFF_UP2) {
    c = r - OFF_UP1; OC = 128;
    src = up_w1 + (size_t)e * 36864;
  } else if (r < OFF_TAIL) {
    c = r - OFF_UP2; OC = 128;
    src = up_w2 + (size_t)e * 36864;
  } else {
    c = r - OFF_TAIL; OC = 3;
    src = tail_w + (size_t)e * 864;
  }
  int tap = c / (OC * 32);
  int rem = c % (OC * 32);
  int och = rem / 32, ich = rem % 32;
  wt[idx] = f2bf(src[(och * 32 + ich) * 9 + tap]);
}

// ---------------- classifier stage A ----------------
__global__ __launch_bounds__(256) void k_cls_conv(
    const float* __restrict__ x, const float* __restrict__ cw,
    const float* __restrict__ cb, float* __restrict__ part) {
  int n = blockIdx.y, band = blockIdx.x, t = threadIdx.x;
  int og = t >> 6, r = (t >> 3) & 7, cg = t & 7;
  int c0 = cg * 4;
  __shared__ float wl[3 * 32 * 9];
  __shared__ float tile[3 * 10 * 34];
  for (int k = t; k < 864; k += 256) {
    int o = k / 27;
    int rem = k % 27;
    int ci = rem / 9, tap = rem % 9;
    wl[(ci * 32 + o) * 9 + tap] = cw[k];
  }
  const float* inb = x + (size_t)n * 3072;
  for (int k = t; k < 1020; k += 256) {
    int ci = k / 340;
    int rem = k % 340;
    int lr = rem / 34, lc = rem % 34;
    int gr = band * 8 - 1 + lr, gc = lc - 1;
    float v = 0.f;
    if (gr >= 0 && gr < 32 && gc >= 0 && gc < 32) v = inb[(ci * 32 + gr) * 32 + gc];
    tile[k] = v;
  }
  __syncthreads();
  float acc[8][4];
#pragma unroll
  for (int oi = 0; oi < 8; ++oi) {
    float b = cb[og * 8 + oi];
#pragma unroll
    for (int p = 0; p < 4; ++p) acc[oi][p] = b;
  }
#pragma unroll
  for (int ci = 0; ci < 3; ++ci) {
    float iv[3][6];
#pragma unroll
    for (int ky = 0; ky < 3; ++ky)
#pragma unroll
      for (int dx = 0; dx < 6; ++dx)
        iv[ky][dx] = tile[ci * 340 + (r + ky) * 34 + c0 + dx];
#pragma unroll
    for (int oi = 0; oi < 8; ++oi) {
      const float* w9 = &wl[((size_t)ci * 32 + og * 8 + oi) * 9];
#pragma unroll
      for (int ky = 0; ky < 3; ++ky)
#pragma unroll
        for (int kx = 0; kx < 3; ++kx) {
          float wv = w9[ky * 3 + kx];
#pragma unroll
          for (int p = 0; p < 4; ++p) acc[oi][p] += wv * iv[ky][p + kx];
        }
    }
  }
#pragma unroll
  for (int oi = 0; oi < 8; ++oi) {
    float s = relu_f(acc[oi][0]) + relu_f(acc[oi][1]) + relu_f(acc[oi][2]) + relu_f(acc[oi][3]);
#pragma unroll
    for (int off = 32; off >= 1; off >>= 1) s += __shfl_down(s, off, 64);
    if ((t & 63) == 0) part[((size_t)n * 4 + band) * 32 + og * 8 + oi] = s;
  }
}

// ---------------- classifier stage B ----------------
__global__ void k_cls_score(const float* __restrict__ part, const float* __restrict__ fw,
                            const float* __restrict__ fb, int* __restrict__ assign, int N) {
  int n = blockIdx.x * blockDim.x + threadIdx.x;
  if (n >= N) return;
  float cm[32];
#pragma unroll
  for (int o = 0; o < 32; ++o) {
    float s = part[((size_t)n * 4 + 0) * 32 + o] + part[((size_t)n * 4 + 1) * 32 + o] +
              part[((size_t)n * 4 + 2) * 32 + o] + part[((size_t)n * 4 + 3) * 32 + o];
    cm[o] = s * (1.f / 1024.f);
  }
  float best = -1e30f;
  int bi = 0;
  for (int e = 0; e < EXPN; ++e) {
    float sc = fb[e];
#pragma unroll
    for (int o = 0; o < 32; ++o) sc += cm[o] * fw[e * 32 + o];
    if (sc > best) { best = sc; bi = e; }
  }
  assign[n] = bi;
}

// ---------------- routing ----------------
__global__ void k_route(const int* __restrict__ assign, int* __restrict__ slot_img, int N) {
  if (threadIdx.x == 0 && blockIdx.x == 0) {
    int cnt[EXPN];
    for (int e = 0; e < EXPN; ++e) cnt[e] = 0;
    for (int k = 0; k < NSLOT; ++k) slot_img[k] = -1;
    for (int n = 0; n < N; ++n) {
      int e = assign[n];
      if (cnt[e] < CAP) { slot_img[e * CAP + cnt[e]] = n; cnt[e]++; }
    }
  }
}

// ---------------- head: conv 3->32 fp32 VALU, store bf16 channel-last to h ----------------
__global__ __launch_bounds__(256) void k_head(
    const float* __restrict__ x, unsigned short* __restrict__ hbuf,
    const float* __restrict__ wglob, const float* __restrict__ bglob,
    const int* __restrict__ slot_img) {
  int slot = blockIdx.y;
  int img = slot_img[slot];
  if (img < 0) return;
  int e = slot / CAP;
  int band = blockIdx.x;
  int t = threadIdx.x;
  int og = t >> 6, r = (t >> 3) & 7, cg = t & 7;
  int c0 = cg * 4;
  __shared__ float wl[3 * 32 * 9];
  __shared__ float tile[3 * 10 * 34];
  __shared__ __align__(16) unsigned short ostg[256 * 32];
  const float* wsrc = wglob + (size_t)e * 32 * 27;
  for (int k = t; k < 864; k += 256) {
    int o = k / 27;
    int rem = k % 27;
    int ci = rem / 9, tap = rem % 9;
    wl[(ci * 32 + o) * 9 + tap] = wsrc[k];
  }
  const float* bsrc = bglob + (size_t)e * 32;
  const float* inb = x + (size_t)img * 3072;
  for (int k = t; k < 3 * 10 * 34; k += 256) {
    int ci = k / 340;
    int rem = k % 340;
    int lr = rem / 34, lc = rem % 34;
    int gr = band * 8 - 1 + lr, gc = lc - 1;
    float v = 0.f;
    if (gr >= 0 && gr < 32 && gc >= 0 && gc < 32) v = inb[(ci * 32 + gr) * 32 + gc];
    tile[k] = v;
  }
  __syncthreads();
  float acc[8][4];
#pragma unroll
  for (int oi = 0; oi < 8; ++oi) {
    float b = bsrc[og * 8 + oi];
#pragma unroll
    for (int p = 0; p < 4; ++p) acc[oi][p] = b;
  }
#pragma unroll
  for (int ci = 0; ci < 3; ++ci) {
    float iv[3][6];
#pragma unroll
    for (int ky = 0; ky < 3; ++ky)
#pragma unroll
      for (int dx = 0; dx < 6; ++dx)
        iv[ky][dx] = tile[ci * 340 + (r + ky) * 34 + c0 + dx];
#pragma unroll
    for (int oi = 0; oi < 8; ++oi) {
      const float* w9 = &wl[((size_t)ci * 32 + og * 8 + oi) * 9];
#pragma unroll
      for (int ky = 0; ky < 3; ++ky)
#pragma unroll
        for (int kx = 0; kx < 3; ++kx) {
          float wv = w9[ky * 3 + kx];
#pragma unroll
          for (int p = 0; p < 4; ++p) acc[oi][p] += wv * iv[ky][p + kx];
        }
    }
  }
#pragma unroll
  for (int oi = 0; oi < 8; ++oi)
#pragma unroll
    for (int p = 0; p < 4; ++p)
      ostg[(r * 32 + c0 + p) * 32 + og * 8 + oi] = f2bf(acc[oi][p]);
  __syncthreads();
  for (int u = t; u < 1024; u += 256) {
    int px = u >> 2, c8 = (u & 3) * 8;
    int4 v = *(const int4*)&ostg[px * 32 + c8];
    size_t gi = ((size_t)slot * 1024 + band * 256 + px) * 32 + c8;
    *(int4*)&hbuf[gi] = v;
  }
}

// ---------------- body conv32 helper (8-wave, 4 rows/wave, ky/kx-outer interleave) ----------------
// EPI 0: relu -> dstP ; EPI 1: dstP += 0.1*y (rmw) ; EPI 2: y + h -> dstP
template <int EPI>
static __device__ __forceinline__ void conv32_lds8(
    const unsigned short* __restrict__ srcP, unsigned short* __restrict__ dstP,
    const unsigned short* __restrict__ hb, unsigned short* __restrict__ wscr,
    const unsigned short* __restrict__ wtc, const float* __restrict__ bsrc,
    int w, int l, int col, int s4) {
  bf16x8 Bf[9][2];
  float bias[2];
#pragma unroll
  for (int n = 0; n < 2; ++n) {
    bias[n] = bsrc[n * 16 + col];
#pragma unroll
    for (int tap = 0; tap < 9; ++tap)
      Bf[tap][n] = *(const bf16x8*)&wtc[((tap * 32) + n * 16 + col) * 32 + s4 * 8];
  }
  int rbase = w * 4;
#pragma unroll
  for (int xh = 0; xh < 2; ++xh) {
    int x0 = xh * 16;
    bf16x8 Af[6][3];
#pragma unroll
    for (int rr = 0; rr < 6; ++rr)
#pragma unroll
      for (int kx = 0; kx < 3; ++kx)
        Af[rr][kx] = *(const bf16x8*)&srcP[(((rbase + rr) * 34) + x0 + col + kx) * 32 + s4 * 8];
    f32x4 acc[4][2];
#pragma unroll
    for (int m = 0; m < 4; ++m)
#pragma unroll
      for (int n = 0; n < 2; ++n) acc[m][n] = (f32x4){bias[n], bias[n], bias[n], bias[n]};
#pragma unroll
    for (int ky = 0; ky < 3; ++ky)
#pragma unroll
      for (int kx = 0; kx < 3; ++kx)
#pragma unroll
        for (int r = 0; r < 4; ++r)
#pragma unroll
          for (int n = 0; n < 2; ++n)
            acc[r][n] = mfma16(Af[r + ky][kx], Bf[ky * 3 + kx][n], acc[r][n]);
#pragma unroll
    for (int r = 0; r < 4; ++r) {
      int row = rbase + r;
#pragma unroll
      for (int n = 0; n < 2; ++n)
#pragma unroll
        for (int reg = 0; reg < 4; ++reg) {
          float v = acc[r][n][reg];
          if (EPI == 0) v = relu_f(v);
          wscr[(s4 * 4 + reg) * 32 + n * 16 + col] = f2bf(v);
        }
      int px2 = l >> 2, c8 = (l & 3) * 8;
      int4 yv = *(const int4*)&wscr[px2 * 32 + c8];
      int x = x0 + px2;
      unsigned li = (unsigned)(((row + 1) * 34 + (x + 1)) * 32 + c8);
      if (EPI == 1) {
        int4 rv = *(const int4*)&dstP[li];
        unsigned short* yp = (unsigned short*)&yv;
        unsigned short* rp = (unsigned short*)&rv;
#pragma unroll
        for (int j = 0; j < 8; ++j) yp[j] = f2bf(bf2f(rp[j]) + 0.1f * bf2f(yp[j]));
        *(int4*)&dstP[li] = yv;
      } else if (EPI == 2) {
        int4 hv = *(const int4*)&hb[((size_t)row * 32 + x) * 32 + c8];
        unsigned short* yp = (unsigned short*)&yv;
        unsigned short* hp = (unsigned short*)&hv;
#pragma unroll
        for (int j = 0; j < 8; ++j) yp[j] = f2bf(bf2f(hp[j]) + bf2f(yp[j]));
        *(int4*)&dstP[li] = yv;
      } else {
        *(int4*)&dstP[li] = yv;
      }
    }
  }
}

// ---------------- body mega-kernel: 4 ResBlocks + end(+h) + up1, all in LDS ----------------
__global__ __launch_bounds__(512, 2) void k_body(
    const unsigned short* __restrict__ hbuf, unsigned short* __restrict__ u1,
    const unsigned short* __restrict__ wt,
    const float* __restrict__ rb_b1, const float* __restrict__ rb_b2,
    const float* __restrict__ end_b, const float* __restrict__ up_b1,
    const int* __restrict__ slot_img) {
  int slot = blockIdx.x;
  int img = slot_img[slot];
  if (img < 0) return;
  int e = slot / CAP;
  int t = threadIdx.x;
  int w = t >> 6, l = t & 63;
  int col = l & 15, s4 = l >> 4;

  __shared__ __align__(16) unsigned short resP[34 * 34 * 32];
  __shared__ __align__(16) unsigned short tP[34 * 34 * 32];
  __shared__ __align__(16) unsigned short scr[8 * 512];

  int4 z = make_int4(0, 0, 0, 0);
  for (int u = t; u < 4624; u += 512) {
    *(int4*)&resP[u * 8] = z;
    *(int4*)&tP[u * 8] = z;
  }
  __syncthreads();
  const unsigned short* hsl = hbuf + (size_t)slot * 32768;
  for (int u = t; u < 4096; u += 512) {
    int px = u >> 2, c8 = (u & 3) * 8;
    *(int4*)&resP[(((px >> 5) + 1) * 34 + (px & 31) + 1) * 32 + c8] =
        *(const int4*)&hsl[px * 32 + c8];
  }
  __syncthreads();

  unsigned short* wscr = &scr[w * 512];
  const unsigned short* wte = wt + (size_t)e * PER_E;

  for (int i = 0; i < NBLK; ++i) {
    conv32_lds8<0>(resP, tP, nullptr, wscr, wte + OFF_RB1 + i * 9216,
                   rb_b1 + (size_t)e * NBLK * 32 + i * 32, w, l, col, s4);
    __syncthreads();
    conv32_lds8<1>(tP, resP, nullptr, wscr, wte + OFF_RB2 + i * 9216,
                   rb_b2 + (size_t)e * NBLK * 32 + i * 32, w, l, col, s4);
    __syncthreads();
  }
  conv32_lds8<2>(resP, tP, hsl, wscr, wte + OFF_END, end_b + (size_t)e * 32, w, l, col, s4);
  __syncthreads();

  // up1: conv 32->128 + pixel shuffle -> u1 [slot][64][64][32]
  {
    int og = w >> 1, rh = w & 1;
    const unsigned short* wtc = wte + OFF_UP1;
    const float* bsrc = up_b1 + (size_t)e * 128;
    bf16x8 Bf[9][2];
    float bias[2];
#pragma unroll
    for (int n = 0; n < 2; ++n) {
      int och = og * 32 + n * 16 + col;
      bias[n] = bsrc[och];
#pragma unroll
      for (int tap = 0; tap < 9; ++tap)
        Bf[tap][n] = *(const bf16x8*)&wtc[((tap * 128) + och) * 32 + s4 * 8];
    }
    unsigned short* u1g = u1 + (size_t)slot * 64 * 64 * 32;
#pragma unroll
    for (int xh = 0; xh < 2; ++xh) {
      int x0 = xh * 16;
#pragma unroll
      for (int rg = 0; rg < 4; ++rg) {
        int rbase = rh * 16 + rg * 4;
        bf16x8 Af[6][3];
#pragma unroll
        for (int rr = 0; rr < 6; ++rr)
#pragma unroll
          for (int kx = 0; kx < 3; ++kx)
            Af[rr][kx] = *(const bf16x8*)&tP[(((rbase + rr) * 34) + x0 + col + kx) * 32 + s4 * 8];
        f32x4 acc[4][2];
#pragma unroll
        for (int m = 0; m < 4; ++m)
#pragma unroll
          for (int n = 0; n < 2; ++n) acc[m][n] = (f32x4){bias[n], bias[n], bias[n], bias[n]};
#pragma unroll
        for (int ky = 0; ky < 3; ++ky)
#pragma unroll
          for (int kx = 0; kx < 3; ++kx)
#pragma unroll
            for (int r = 0; r < 4; ++r)
#pragma unroll
              for (int n = 0; n < 2; ++n)
                acc[r][n] = mfma16(Af[r + ky][kx], Bf[ky * 3 + kx][n], acc[r][n]);
#pragma unroll
        for (int r = 0; r < 4; ++r) {
          int row = rbase + r;
#pragma unroll
          for (int n = 0; n < 2; ++n) {
            int och = og * 32 + n * 16 + col;
            int ryrx = och & 3, ccl = (och >> 2) & 7;
#pragma unroll
            for (int reg = 0; reg < 4; ++reg)
              wscr[(ryrx * 16 + s4 * 4 + reg) * 8 + ccl] = f2bf(acc[r][n][reg]);
          }
          int ryrx2 = l >> 4, px2 = l & 15;
          int4 yv = *(const int4*)&wscr[(ryrx2 * 16 + px2) * 8];
          int ry = ryrx2 >> 1, rx = ryrx2 & 1;
          int oy = 2 * row + ry, ox = 2 * (x0 + px2) + rx;
          *(int4*)&u1g[((size_t)oy * 64 + ox) * 32 + og * 8] = yv;
        }
      }
    }
  }
}

// ---------------- up2: conv 32->128 + pixel shuffle, 4-row interleave ----------------
template <int HW>
__global__ __launch_bounds__(256) void k_up(
    const unsigned short* __restrict__ inbuf, unsigned short* __restrict__ outbuf,
    const unsigned short* __restrict__ wt, const float* __restrict__ bglob,
    const int* __restrict__ slot_img, int slot0) {
  int lslot = blockIdx.y;
  int slot = slot0 + lslot;
  int img = slot_img[slot];
  if (img < 0) return;
  int e = slot / CAP;
  int band = blockIdx.x;
  int t = threadIdx.x;
  int w = t >> 6, l = t & 63;
  int col = l & 15, s4 = l >> 4;
  constexpr int XP = HW + 2;
  __shared__ __align__(16) unsigned short tile[4 * 10 * XP * 8];
  __shared__ __align__(16) unsigned short scr[4 * 4 * 16 * 8];
  const unsigned short* inb = inbuf + (size_t)slot * 32 * HW * HW;
  for (int u = t; u < 4 * 10 * XP; u += 256) {
    int s = u / (10 * XP);
    int rem = u - s * (10 * XP);
    int lr = rem / XP, lx = rem - lr * XP;
    int gr = band * 8 - 1 + lr, gx = lx - 1;
    int4 v = make_int4(0, 0, 0, 0);
    if (gr >= 0 && gr < HW && gx >= 0 && gx < HW)
      v = *(const int4*)&inb[(gr * HW + gx) * 32 + s * 8];
    *(int4*)&tile[u * 8] = v;
  }
  const unsigned short* wtc = wt + (size_t)e * PER_E + OFF_UP2;
  const float* bsrc = bglob + (size_t)e * 128;
  bf16x8 Bf[9][2];
  float bias[2];
#pragma unroll
  for (int n = 0; n < 2; ++n) {
    int och = w * 32 + n * 16 + col;
    bias[n] = bsrc[och];
#pragma unroll
    for (int tap = 0; tap < 9; ++tap)
      Bf[tap][n] = *(const bf16x8*)&wtc[((tap * 128) + och) * 32 + s4 * 8];
  }
  __syncthreads();
  unsigned short* wscr = &scr[w * 512];
  unsigned short* outb = outbuf + (size_t)(slot - slot0) * (2 * HW) * (2 * HW) * 32;
  for (int h = 0; h < HW / 16; ++h) {
#pragma unroll
    for (int rg = 0; rg < 2; ++rg) {
      int rbase = rg * 4;
      bf16x8 Af[6][3];
#pragma unroll
      for (int rr = 0; rr < 6; ++rr)
#pragma unroll
        for (int kx = 0; kx < 3; ++kx)
          Af[rr][kx] =
              *(const bf16x8*)&tile[((s4 * 10 + rbase + rr) * XP + h * 16 + kx + col) * 8];
      f32x4 acc[4][2];
#pragma unroll
      for (int m = 0; m < 4; ++m)
#pragma unroll
        for (int n = 0; n < 2; ++n) acc[m][n] = (f32x4){bias[n], bias[n], bias[n], bias[n]};
#pragma unroll
      for (int ky = 0; ky < 3; ++ky)
#pragma unroll
        for (int kx = 0; kx < 3; ++kx)
#pragma unroll
          for (int r = 0; r < 4; ++r)
#pragma unroll
            for (int n = 0; n < 2; ++n)
              acc[r][n] = mfma16(Af[r + ky][kx], Bf[ky * 3 + kx][n], acc[r][n]);
#pragma unroll
      for (int r = 0; r < 4; ++r) {
        int row = band * 8 + rbase + r;
#pragma unroll
        for (int n = 0; n < 2; ++n) {
          int och = w * 32 + n * 16 + col;
          int ryrx = och & 3, ccl = (och >> 2) & 7;
#pragma unroll
          for (int reg = 0; reg < 4; ++reg)
            wscr[(ryrx * 16 + s4 * 4 + reg) * 8 + ccl] = f2bf(acc[r][n][reg]);
        }
        int ryrx2 = l >> 4, px2 = l & 15;
        int4 yv = *(const int4*)&wscr[(ryrx2 * 16 + px2) * 8];
        int ry = ryrx2 >> 1, rx = ryrx2 & 1;
        int oy = 2 * row + ry, ox = 2 * (h * 16 + px2) + rx;
        size_t oi = ((size_t)oy * (2 * HW) + ox) * 32 + w * 8;
        *(int4*)&outb[oi] = yv;
      }
    }
  }
}

// ---------------- tail conv 32->3 @128x128, 4-row interleave, fp32 gather-write ----------------
__global__ __launch_bounds__(256) void k_tail(
    const unsigned short* __restrict__ inbuf, float* __restrict__ out,
    const unsigned short* __restrict__ wt, const float* __restrict__ bglob,
    const int* __restrict__ slot_img, int slot0) {
  int lslot = blockIdx.y;
  int slot = slot0 + lslot;
  int img = slot_img[slot];
  if (img < 0) return;
  int e = slot / CAP;
  int band = blockIdx.x & 15, xh = blockIdx.x >> 4;
  int t = threadIdx.x;
  int w = t >> 6, l = t & 63;
  int col = l & 15, s4 = l >> 4;
  __shared__ __align__(16) unsigned short tile[4 * 10 * 66 * 8];
  const unsigned short* inb = inbuf + (size_t)lslot * 128 * 128 * 32;
  for (int u = t; u < 2640; u += 256) {
    int s = u / 660;
    int rem = u - s * 660;
    int lr = rem / 66, lx = rem - lr * 66;
    int gr = band * 8 - 1 + lr, gx = xh * 64 - 1 + lx;
    int4 v = make_int4(0, 0, 0, 0);
    if (gr >= 0 && gr < 128 && gx >= 0 && gx < 128)
      v = *(const int4*)&inb[(gr * 128 + gx) * 32 + s * 8];
    *(int4*)&tile[u * 8] = v;
  }
  const unsigned short* wtc = wt + (size_t)e * PER_E + OFF_TAIL;
  bf16x8 Bf[9];
  float bias = 0.f;
  if (col < 3) bias = bglob[e * 3 + col];
#pragma unroll
  for (int tap = 0; tap < 9; ++tap) {
    if (col < 3)
      Bf[tap] = *(const bf16x8*)&wtc[((tap * 3) + col) * 32 + s4 * 8];
    else {
      bf16x8 bb;
#pragma unroll
      for (int j = 0; j < 8; ++j) bb[j] = (short)0;
      Bf[tap] = bb;
    }
  }
  __syncthreads();
  int hh = w;
#pragma unroll
  for (int rg = 0; rg < 2; ++rg) {
    int rbase = rg * 4;
    bf16x8 Af[6][3];
#pragma unroll
    for (int rr = 0; rr < 6; ++rr)
#pragma unroll
      for (int kx = 0; kx < 3; ++kx)
        Af[rr][kx] = *(const bf16x8*)&tile[((s4 * 10 + rbase + rr) * 66 + hh * 16 + kx + col) * 8];
    f32x4 acc[4];
#pragma unroll
    for (int r = 0; r < 4; ++r) acc[r] = (f32x4){bias, bias, bias, bias};
#pragma unroll
    for (int ky = 0; ky < 3; ++ky)
#pragma unroll
      for (int kx = 0; kx < 3; ++kx)
#pragma unroll
        for (int r = 0; r < 4; ++r)
          acc[r] = mfma16(Af[r + ky][kx], Bf[ky * 3 + kx], acc[r]);
    if (col < 3) {
#pragma unroll
      for (int r = 0; r < 4; ++r) {
        int grow = band * 8 + rbase + r, gx0 = xh * 64 + hh * 16 + s4 * 4;
        *(float4*)&out[(((size_t)img * 3 + col) * 128 + grow) * 128 + gx0] =
            make_float4(acc[r][0], acc[r][1], acc[r][2], acc[r][3]);
      }
    }
  }
}

extern "C" void kernel_launch(void* const* d_in, const int* in_sizes, int n_in,
                              void* d_out, int out_size, void* d_ws, size_t ws_size,
                              hipStream_t stream) {
  const float* inputs = (const float*)d_in[0];
  const float* cls_w = (const float*)d_in[1];
  const float* cls_b = (const float*)d_in[2];
  const float* cls_fw = (const float*)d_in[3];
  const float* cls_fb = (const float*)d_in[4];
  const float* head_w = (const float*)d_in[5];
  const float* head_b = (const float*)d_in[6];
  const float* rb_w1 = (const float*)d_in[7];
  const float* rb_b1 = (const float*)d_in[8];
  const float* rb_w2 = (const float*)d_in[9];
  const float* rb_b2 = (const float*)d_in[10];
  const float* end_w = (const float*)d_in[11];
  const float* end_b = (const float*)d_in[12];
  const float* up_w1 = (const float*)d_in[13];
  const float* up_b1 = (const float*)d_in[14];
  const float* up_w2 = (const float*)d_in[15];
  const float* up_b2 = (const float*)d_in[16];
  const float* tail_w = (const float*)d_in[17];
  const float* tail_b = (const float*)d_in[18];
  float* out = (float*)d_out;
  char* ws = (char*)d_ws;

  int N = in_sizes[0] / 3072;  // 128

  int* assign = (int*)ws;
  int* slot_img = (int*)(ws + 512);
  float* part = (float*)(ws + 4096);                     // [N][4][32]
  unsigned short* wt = (unsigned short*)(ws + 131072);   // 1.26 MB transformed weights
  const size_t ABUF = (size_t)NSLOT * 1024 * 32 * 2;     // 12,582,912
  const size_t U1B = (size_t)NSLOT * 64 * 64 * 32 * 2;   // 50,331,648
  const size_t SLOT_U2 = (size_t)128 * 128 * 32 * 2;     // 1,048,576
  size_t o_h = 1572864;
  unsigned short* h = (unsigned short*)(ws + o_h);
  unsigned short* u1 = (unsigned short*)(ws + o_h + ABUF);
  size_t o_u2full = o_h + ABUF + U1B;  // ~64.5 MB

  unsigned short* u2;
  int CH;
  size_t tail_avail = (ws_size > o_u2full) ? (ws_size - o_u2full) : 0;
  int CH_tail = (int)(tail_avail / SLOT_U2);
  const int CH_alias = (int)(ABUF / SLOT_U2);  // 12 (h dead after body)
  if (CH_tail >= CH_alias) {
    u2 = (unsigned short*)(ws + o_u2full);
    CH = CH_tail < NSLOT ? CH_tail : NSLOT;
  } else {
    u2 = (unsigned short*)(ws + o_h);
    CH = CH_alias;
  }
  if (CH < 1) CH = 1;

  k_zero<<<2048, 256, 0, stream>>>((float4*)out, out_size / 4);
  k_wxform<<<(EXPN * PER_E + 255) / 256, 256, 0, stream>>>(
      rb_w1, rb_w2, end_w, up_w1, up_w2, tail_w, wt);
  k_cls_conv<<<dim3(4, N), 256, 0, stream>>>(inputs, cls_w, cls_b, part);
  k_cls_score<<<(N + 63) / 64, 64, 0, stream>>>(part, cls_fw, cls_fb, assign, N);
  k_route<<<1, 64, 0, stream>>>(assign, slot_img, N);

  k_head<<<dim3(4, NSLOT), 256, 0, stream>>>(inputs, h, head_w, head_b, slot_img);

  k_body<<<NSLOT, 512, 0, stream>>>(h, u1, wt, rb_b1, rb_b2, end_b, up_b1, slot_img);

  for (int s0 = 0; s0 < NSLOT; s0 += CH) {
    int cur = (NSLOT - s0) < CH ? (NSLOT - s0) : CH;
    k_up<64><<<dim3(8, cur), 256, 0, stream>>>(u1, u2, wt, up_b2, slot_img, s0);
    k_tail<<<dim3(32, cur), 256, 0, stream>>>(u2, out, wt, tail_b, slot_img, s0);
  }
}